// Round 1
// baseline (1441.780 us; speedup 1.0000x reference)
//
#include <hip/hip_runtime.h>
#include <math.h>

// Problem constants
#define NB   2048
#define NFC  171
#define NFR  171
#define NL   32
#define NH   256
#define NE   16
#define NGH  64
#define NIN  203   /* L + FC */
#define NINT 288   /* L + H  */
#define NOUT 171

__device__ __forceinline__ float elu_f(float v) {
    return v > 0.0f ? v : expm1f(v);
}

// ---------------------------------------------------------------------------
// Generic tiled GEMM: out = ELU( concat(A1,A2) @ Bw + bias )
// A1: [2048, ld1] uses cols [0,K1); A2: [2048, ld2] cols [K1,K)
// Bw: [K, N] row-major. out: [2048, N].
// Tile: BM=64, BN=64, BK=32, 256 threads, 4x4 micro-tile.
// grid = (N/64, 2048/64)
// ---------------------------------------------------------------------------
__global__ __launch_bounds__(256) void gemm_cat_elu(
    const float* __restrict__ A1, int ld1, int K1,
    const float* __restrict__ A2, int ld2, int K,
    const float* __restrict__ Bw, int N,
    const float* __restrict__ bias,
    float* __restrict__ out)
{
    const int bn = blockIdx.x, bm = blockIdx.y;
    const int tid = threadIdx.x;
    const int tx = tid & 15, ty = tid >> 4;
    const int brow = bm * 64, bcol = bn * 64;

    __shared__ float As[32][65];   // transposed: As[k][r]
    __shared__ float Bs[32][64];   // Bs[k][c]

    float acc[4][4] = {};

    for (int k0 = 0; k0 < K; k0 += 32) {
        // stage A (64 rows x 32 k), transposed into LDS
#pragma unroll
        for (int i = 0; i < 8; ++i) {
            int idx = i * 256 + tid;         // 0..2047
            int r = idx >> 5, k = idx & 31;
            int gk = k0 + k;
            float v = 0.0f;
            if (gk < K1)      v = A1[(brow + r) * ld1 + gk];
            else if (gk < K)  v = A2[(brow + r) * ld2 + (gk - K1)];
            As[k][r] = v;
        }
        // stage B (32 k x 64 cols)
#pragma unroll
        for (int i = 0; i < 8; ++i) {
            int idx = i * 256 + tid;
            int k = idx >> 6, c = idx & 63;
            int gk = k0 + k;
            Bs[k][c] = (gk < K) ? Bw[gk * N + bcol + c] : 0.0f;
        }
        __syncthreads();
#pragma unroll
        for (int kk = 0; kk < 32; ++kk) {
            float a0 = As[kk][ty * 4 + 0];
            float a1 = As[kk][ty * 4 + 1];
            float a2 = As[kk][ty * 4 + 2];
            float a3 = As[kk][ty * 4 + 3];
            const float4 b = *(const float4*)&Bs[kk][tx * 4];
            acc[0][0] += a0 * b.x; acc[0][1] += a0 * b.y; acc[0][2] += a0 * b.z; acc[0][3] += a0 * b.w;
            acc[1][0] += a1 * b.x; acc[1][1] += a1 * b.y; acc[1][2] += a1 * b.z; acc[1][3] += a1 * b.w;
            acc[2][0] += a2 * b.x; acc[2][1] += a2 * b.y; acc[2][2] += a2 * b.z; acc[2][3] += a2 * b.w;
            acc[3][0] += a3 * b.x; acc[3][1] += a3 * b.y; acc[3][2] += a3 * b.z; acc[3][3] += a3 * b.w;
        }
        __syncthreads();
    }

#pragma unroll
    for (int i = 0; i < 4; ++i) {
        int row = brow + ty * 4 + i;
#pragma unroll
        for (int j = 0; j < 4; ++j) {
            int col = bcol + tx * 4 + j;
            out[row * N + col] = elu_f(acc[i][j] + bias[col]);
        }
    }
}

// ---------------------------------------------------------------------------
// mu/logvar GEMM + z.  A = [x(171) | h2(256)], K=427.
// B cols 0..31 = mu_w, 32..63 = lv_w (both [427,32]).
// Writes mu, logvar to d_out regions; z = mu + eps*exp(0.5*lv) to ws.
// BM=64, BN=64(fixed), grid = (32)
// ---------------------------------------------------------------------------
__global__ __launch_bounds__(256) void gemm_mulv(
    const float* __restrict__ x, const float* __restrict__ h2,
    const float* __restrict__ muw, const float* __restrict__ mub,
    const float* __restrict__ lvw, const float* __restrict__ lvb,
    const float* __restrict__ eps,
    float* __restrict__ mu_out, float* __restrict__ lv_out,
    float* __restrict__ z_out)
{
    const int bm = blockIdx.x;
    const int tid = threadIdx.x;
    const int tx = tid & 15, ty = tid >> 4;
    const int brow = bm * 64;
    const int K = 427, K1 = 171;

    __shared__ float As[32][65];
    __shared__ float Bs[32][64];
    __shared__ float Tile[64][65];

    float acc[4][4] = {};

    for (int k0 = 0; k0 < K; k0 += 32) {
#pragma unroll
        for (int i = 0; i < 8; ++i) {
            int idx = i * 256 + tid;
            int r = idx >> 5, k = idx & 31;
            int gk = k0 + k;
            float v = 0.0f;
            if (gk < K1)      v = x[(brow + r) * 171 + gk];
            else if (gk < K)  v = h2[(brow + r) * 256 + (gk - K1)];
            As[k][r] = v;
        }
#pragma unroll
        for (int i = 0; i < 8; ++i) {
            int idx = i * 256 + tid;
            int k = idx >> 6, c = idx & 63;
            int gk = k0 + k;
            float v = 0.0f;
            if (gk < K) v = (c < 32) ? muw[gk * 32 + c] : lvw[gk * 32 + (c - 32)];
            Bs[k][c] = v;
        }
        __syncthreads();
#pragma unroll
        for (int kk = 0; kk < 32; ++kk) {
            float a0 = As[kk][ty * 4 + 0];
            float a1 = As[kk][ty * 4 + 1];
            float a2 = As[kk][ty * 4 + 2];
            float a3 = As[kk][ty * 4 + 3];
            const float4 b = *(const float4*)&Bs[kk][tx * 4];
            acc[0][0] += a0 * b.x; acc[0][1] += a0 * b.y; acc[0][2] += a0 * b.z; acc[0][3] += a0 * b.w;
            acc[1][0] += a1 * b.x; acc[1][1] += a1 * b.y; acc[1][2] += a1 * b.z; acc[1][3] += a1 * b.w;
            acc[2][0] += a2 * b.x; acc[2][1] += a2 * b.y; acc[2][2] += a2 * b.z; acc[2][3] += a2 * b.w;
            acc[3][0] += a3 * b.x; acc[3][1] += a3 * b.y; acc[3][2] += a3 * b.z; acc[3][3] += a3 * b.w;
        }
        __syncthreads();
    }

#pragma unroll
    for (int i = 0; i < 4; ++i) {
        int r = ty * 4 + i;
        int row = brow + r;
#pragma unroll
        for (int j = 0; j < 4; ++j) {
            int col = tx * 4 + j;
            float v = acc[i][j] + ((col < 32) ? mub[col] : lvb[col - 32]);
            Tile[r][col] = v;
            if (col < 32) mu_out[row * 32 + col] = v;
            else          lv_out[row * 32 + (col - 32)] = v;
        }
    }
    __syncthreads();
    // z = mu + eps * exp(0.5*logvar)
    for (int idx = tid; idx < 64 * 32; idx += 256) {
        int r = idx >> 5, l = idx & 31;
        float mu = Tile[r][l];
        float lv = Tile[r][32 + l];
        int row = brow + r;
        z_out[row * 32 + l] = mu + eps[row * 32 + l] * expf(0.5f * lv);
    }
}

// ---------------------------------------------------------------------------
// Gate MLP + softmax -> coef [2048,16].  gin = [z(32) | c(171)], K=203.
// All gate weights staged in LDS. 8 rows / block, 256 blocks.
// ---------------------------------------------------------------------------
__global__ __launch_bounds__(256) void gate_kernel(
    const float* __restrict__ z, const float* __restrict__ c,
    const float* __restrict__ g0w, const float* __restrict__ g0b,
    const float* __restrict__ g1w, const float* __restrict__ g1b,
    const float* __restrict__ g2w, const float* __restrict__ g2b,
    float* __restrict__ coef)
{
    __shared__ float W0[NIN * NGH];   // 203*64
    __shared__ float W1[NGH * NGH];   // 64*64
    __shared__ float W2[NGH * NE];    // 64*16
    __shared__ float B0[NGH], B1[NGH], B2[NE];
    __shared__ float GIN[8][204];

    const int tid = threadIdx.x;
    for (int i = tid; i < NIN * NGH; i += 256) W0[i] = g0w[i];
    for (int i = tid; i < NGH * NGH; i += 256) W1[i] = g1w[i];
    for (int i = tid; i < NGH * NE;  i += 256) W2[i] = g2w[i];
    if (tid < NGH) { B0[tid] = g0b[tid]; B1[tid] = g1b[tid]; }
    if (tid < NE)  { B2[tid] = g2b[tid]; }

    const int row0 = blockIdx.x * 8;
    for (int idx = tid; idx < 8 * NIN; idx += 256) {
        int rr = idx / NIN, i = idx - rr * NIN;
        GIN[rr][i] = (i < 32) ? z[(row0 + rr) * 32 + i]
                              : c[(row0 + rr) * 171 + (i - 32)];
    }
    __syncthreads();

    const int wave = tid >> 6, lane = tid & 63;
#pragma unroll
    for (int rw = 0; rw < 2; ++rw) {
        int rr = wave * 2 + rw;
        int row = row0 + rr;
        // layer g0: each lane computes output neuron 'lane'
        float a = B0[lane];
        for (int k = 0; k < NIN; ++k) a += GIN[rr][k] * W0[k * NGH + lane];
        float h = elu_f(a);
        // layer g1 via wave shuffles
        float a1 = B1[lane];
#pragma unroll
        for (int k = 0; k < NGH; ++k) a1 += __shfl(h, k, 64) * W1[k * NGH + lane];
        float h2 = elu_f(a1);
        // layer g2 (16 outputs; every group of 16 lanes computes same col)
        int o = lane & 15;
        float a2 = B2[o];
#pragma unroll
        for (int k = 0; k < NGH; ++k) a2 += __shfl(h2, k, 64) * W2[k * NE + o];
        // softmax over 16
        float m = a2;
        for (int off = 1; off < 16; off <<= 1) m = fmaxf(m, __shfl_xor(m, off, 16));
        float ev = expf(a2 - m);
        float s = ev;
        for (int off = 1; off < 16; off <<= 1) s += __shfl_xor(s, off, 16);
        if (lane < 16) coef[row * 16 + lane] = ev / s;
    }
}

// ---------------------------------------------------------------------------
// MoE layer: out[b,o] = act( sum_e coef[b,e] * ( [z|lay][b,:] @ W[e,:,o] + bb[e,o] ) )
// A staged once full-K (transposed) in LDS; B per (expert, k-tile).
// BM=32, BN=64, 256 threads, 2x4 micro-tile.  grid = (ceil(O/64), 64)
// ---------------------------------------------------------------------------
template<bool ACT>
__global__ __launch_bounds__(256) void moe_layer(
    const float* __restrict__ z,                 // [2048, 32]
    const float* __restrict__ lay, int ldl,      // [2048, ldl]
    int K, int KR,                               // K and K rounded up to 32
    const float* __restrict__ W,                 // [16, K, O]
    const float* __restrict__ bias,              // [16, O]
    const float* __restrict__ coef,              // [2048, 16]
    float* __restrict__ out, int O)
{
    const int bn = blockIdx.x, bm = blockIdx.y;
    const int tid = threadIdx.x;
    const int tx = tid & 15, ty = tid >> 4;
    const int brow = bm * 32, bcol = bn * 64;

    __shared__ float As[NINT][33];   // transposed: As[k][r], KR <= 288
    __shared__ float Bs[32][64];
    __shared__ float Cs[32][16];

    // stage A full K (rounded, zero-padded)
    for (int idx = tid; idx < 32 * KR; idx += 256) {
        int r = idx / KR, k = idx - r * KR;
        float v = 0.0f;
        if (k < 32)      v = z[(brow + r) * 32 + k];
        else if (k < K)  v = lay[(brow + r) * ldl + (k - 32)];
        As[k][r] = v;
    }
    // stage coef for this row block
    {
        int r = tid >> 4, e = tid & 15;
        Cs[r][e]      = coef[(brow + r) * 16 + e];
        Cs[r + 16][e] = coef[(brow + 16 + r) * 16 + e];
    }
    __syncthreads();

    const int r0 = ty * 2, r1 = ty * 2 + 1;
    float outacc[2][4] = {};

    for (int e = 0; e < NE; ++e) {
        float acc[2][4] = {};
        const float* We = W + (size_t)e * K * O;
        for (int k0 = 0; k0 < KR; k0 += 32) {
#pragma unroll
            for (int i = 0; i < 8; ++i) {
                int idx = i * 256 + tid;
                int k = idx >> 6, cc = idx & 63;
                int gk = k0 + k, gc = bcol + cc;
                Bs[k][cc] = (gk < K && gc < O) ? We[gk * O + gc] : 0.0f;
            }
            __syncthreads();
#pragma unroll
            for (int kk = 0; kk < 32; ++kk) {
                float a0 = As[k0 + kk][r0];
                float a1 = As[k0 + kk][r1];
                const float4 b = *(const float4*)&Bs[kk][tx * 4];
                acc[0][0] += a0 * b.x; acc[0][1] += a0 * b.y; acc[0][2] += a0 * b.z; acc[0][3] += a0 * b.w;
                acc[1][0] += a1 * b.x; acc[1][1] += a1 * b.y; acc[1][2] += a1 * b.z; acc[1][3] += a1 * b.w;
            }
            __syncthreads();
        }
        float cf0 = Cs[r0][e], cf1 = Cs[r1][e];
#pragma unroll
        for (int j = 0; j < 4; ++j) {
            int gc = bcol + tx * 4 + j;
            float bv = (gc < O) ? bias[e * O + gc] : 0.0f;
            outacc[0][j] += cf0 * (acc[0][j] + bv);
            outacc[1][j] += cf1 * (acc[1][j] + bv);
        }
    }

#pragma unroll
    for (int i = 0; i < 2; ++i) {
        int row = brow + ty * 2 + i;
#pragma unroll
        for (int j = 0; j < 4; ++j) {
            int gc = bcol + tx * 4 + j;
            if (gc < O) {
                float v = outacc[i][j];
                out[row * O + gc] = ACT ? elu_f(v) : v;
            }
        }
    }
}

// ---------------------------------------------------------------------------
extern "C" void kernel_launch(void* const* d_in, const int* in_sizes, int n_in,
                              void* d_out, int out_size, void* d_ws, size_t ws_size,
                              hipStream_t stream)
{
    const float* x    = (const float*)d_in[0];
    const float* c    = (const float*)d_in[1];
    const float* eps  = (const float*)d_in[2];
    const float* fc1w = (const float*)d_in[3];
    const float* fc1b = (const float*)d_in[4];
    const float* fc2w = (const float*)d_in[5];
    const float* fc2b = (const float*)d_in[6];
    const float* muw  = (const float*)d_in[7];
    const float* mub  = (const float*)d_in[8];
    const float* lvw  = (const float*)d_in[9];
    const float* lvb  = (const float*)d_in[10];
    const float* g0w  = (const float*)d_in[11];
    const float* g0b  = (const float*)d_in[12];
    const float* g1w  = (const float*)d_in[13];
    const float* g1b  = (const float*)d_in[14];
    const float* g2w  = (const float*)d_in[15];
    const float* g2b  = (const float*)d_in[16];
    const float* w0   = (const float*)d_in[17];
    const float* b0   = (const float*)d_in[18];
    const float* w1   = (const float*)d_in[19];
    const float* b1   = (const float*)d_in[20];
    const float* w2   = (const float*)d_in[21];
    const float* b2   = (const float*)d_in[22];

    float* out       = (float*)d_out;
    float* out_layer = out;                       // [2048,171]
    float* out_mu    = out + NB * NOUT;           // [2048,32]
    float* out_lv    = out_mu + NB * NL;          // [2048,32]

    float* ws = (float*)d_ws;
    float* h1 = ws;                 // 2048*256
    float* h2 = h1 + NB * NH;       // 2048*256
    float* zb = h2 + NB * NH;       // 2048*32
    float* cf = zb + NB * NL;       // 2048*16
    float* l0 = h1;                 // reuse (h1 dead after fc2)
    float* l1 = h2;                 // reuse (h2 dead after mulv)

    dim3 blk(256);

    // Encoder
    gemm_cat_elu<<<dim3(4, 32), blk, 0, stream>>>(x, 171, 171, c, 171, 342, fc1w, 256, fc1b, h1);
    gemm_cat_elu<<<dim3(4, 32), blk, 0, stream>>>(x, 171, 171, h1, 256, 427, fc2w, 256, fc2b, h2);
    // mu / logvar / z
    gemm_mulv<<<dim3(32), blk, 0, stream>>>(x, h2, muw, mub, lvw, lvb, eps, out_mu, out_lv, zb);
    // gate -> coef
    gate_kernel<<<dim3(256), blk, 0, stream>>>(zb, x ? (const float*)d_in[1] : c, g0w, g0b, g1w, g1b, g2w, g2b, cf);
    // MoE layers
    moe_layer<true ><<<dim3(4, 64), blk, 0, stream>>>(zb, c, 171, 203, 224, w0, b0, cf, l0, 256);
    moe_layer<true ><<<dim3(4, 64), blk, 0, stream>>>(zb, l0, 256, 288, 288, w1, b1, cf, l1, 256);
    moe_layer<false><<<dim3(3, 64), blk, 0, stream>>>(zb, l1, 256, 288, 288, w2, b2, cf, out_layer, 171);
}

// Round 2
// 331.598 us; speedup vs baseline: 4.3480x; 4.3480x over previous
//
#include <hip/hip_runtime.h>
#include <math.h>

// Problem constants
#define NB   2048
#define NFC  171
#define NFR  171
#define NL   32
#define NH   256
#define NE   16
#define NGH  64
#define NIN  203   /* L + FC */
#define NINT 288   /* L + H  */
#define NOUT 171

typedef __attribute__((ext_vector_type(8))) short bf16x8;   // 8 bf16 in 4 VGPRs
typedef __attribute__((ext_vector_type(4))) float f32x4;    // MFMA acc

__device__ __forceinline__ float elu_f(float v) {
    return v > 0.0f ? v : expm1f(v);
}

// f32 -> bf16 bits, round-to-nearest-even (values are finite)
__device__ __forceinline__ short f2bf(float f) {
    unsigned u = __float_as_uint(f);
    unsigned r = (u + 0x7FFFu + ((u >> 16) & 1u)) >> 16;
    return (short)r;
}

// async global->LDS, 16 bytes per lane; lds base must be wave-uniform
__device__ __forceinline__ void gload16(void* lds, const void* g) {
    __builtin_amdgcn_global_load_lds(
        (const __attribute__((address_space(1))) unsigned*)g,
        (__attribute__((address_space(3))) unsigned*)lds, 16, 0, 0);
}

// ---------------------------------------------------------------------------
// Encoder GEMMs (unchanged from round 1, known-good f32)
// ---------------------------------------------------------------------------
__global__ __launch_bounds__(256) void gemm_cat_elu(
    const float* __restrict__ A1, int ld1, int K1,
    const float* __restrict__ A2, int ld2, int K,
    const float* __restrict__ Bw, int N,
    const float* __restrict__ bias,
    float* __restrict__ out)
{
    const int bn = blockIdx.x, bm = blockIdx.y;
    const int tid = threadIdx.x;
    const int tx = tid & 15, ty = tid >> 4;
    const int brow = bm * 64, bcol = bn * 64;

    __shared__ float As[32][65];
    __shared__ float Bs[32][64];

    float acc[4][4] = {};

    for (int k0 = 0; k0 < K; k0 += 32) {
#pragma unroll
        for (int i = 0; i < 8; ++i) {
            int idx = i * 256 + tid;
            int r = idx >> 5, k = idx & 31;
            int gk = k0 + k;
            float v = 0.0f;
            if (gk < K1)      v = A1[(brow + r) * ld1 + gk];
            else if (gk < K)  v = A2[(brow + r) * ld2 + (gk - K1)];
            As[k][r] = v;
        }
#pragma unroll
        for (int i = 0; i < 8; ++i) {
            int idx = i * 256 + tid;
            int k = idx >> 6, c = idx & 63;
            int gk = k0 + k;
            Bs[k][c] = (gk < K) ? Bw[gk * N + bcol + c] : 0.0f;
        }
        __syncthreads();
#pragma unroll
        for (int kk = 0; kk < 32; ++kk) {
            float a0 = As[kk][ty * 4 + 0];
            float a1 = As[kk][ty * 4 + 1];
            float a2 = As[kk][ty * 4 + 2];
            float a3 = As[kk][ty * 4 + 3];
            const float4 b = *(const float4*)&Bs[kk][tx * 4];
            acc[0][0] += a0 * b.x; acc[0][1] += a0 * b.y; acc[0][2] += a0 * b.z; acc[0][3] += a0 * b.w;
            acc[1][0] += a1 * b.x; acc[1][1] += a1 * b.y; acc[1][2] += a1 * b.z; acc[1][3] += a1 * b.w;
            acc[2][0] += a2 * b.x; acc[2][1] += a2 * b.y; acc[2][2] += a2 * b.z; acc[2][3] += a2 * b.w;
            acc[3][0] += a3 * b.x; acc[3][1] += a3 * b.y; acc[3][2] += a3 * b.z; acc[3][3] += a3 * b.w;
        }
        __syncthreads();
    }

#pragma unroll
    for (int i = 0; i < 4; ++i) {
        int row = brow + ty * 4 + i;
#pragma unroll
        for (int j = 0; j < 4; ++j) {
            int col = bcol + tx * 4 + j;
            out[row * N + col] = elu_f(acc[i][j] + bias[col]);
        }
    }
}

__global__ __launch_bounds__(256) void gemm_mulv(
    const float* __restrict__ x, const float* __restrict__ h2,
    const float* __restrict__ muw, const float* __restrict__ mub,
    const float* __restrict__ lvw, const float* __restrict__ lvb,
    const float* __restrict__ eps,
    float* __restrict__ mu_out, float* __restrict__ lv_out,
    float* __restrict__ z_out)
{
    const int bm = blockIdx.x;
    const int tid = threadIdx.x;
    const int tx = tid & 15, ty = tid >> 4;
    const int brow = bm * 64;
    const int K = 427, K1 = 171;

    __shared__ float As[32][65];
    __shared__ float Bs[32][64];
    __shared__ float Tile[64][65];

    float acc[4][4] = {};

    for (int k0 = 0; k0 < K; k0 += 32) {
#pragma unroll
        for (int i = 0; i < 8; ++i) {
            int idx = i * 256 + tid;
            int r = idx >> 5, k = idx & 31;
            int gk = k0 + k;
            float v = 0.0f;
            if (gk < K1)      v = x[(brow + r) * 171 + gk];
            else if (gk < K)  v = h2[(brow + r) * 256 + (gk - K1)];
            As[k][r] = v;
        }
#pragma unroll
        for (int i = 0; i < 8; ++i) {
            int idx = i * 256 + tid;
            int k = idx >> 6, c = idx & 63;
            int gk = k0 + k;
            float v = 0.0f;
            if (gk < K) v = (c < 32) ? muw[gk * 32 + c] : lvw[gk * 32 + (c - 32)];
            Bs[k][c] = v;
        }
        __syncthreads();
#pragma unroll
        for (int kk = 0; kk < 32; ++kk) {
            float a0 = As[kk][ty * 4 + 0];
            float a1 = As[kk][ty * 4 + 1];
            float a2 = As[kk][ty * 4 + 2];
            float a3 = As[kk][ty * 4 + 3];
            const float4 b = *(const float4*)&Bs[kk][tx * 4];
            acc[0][0] += a0 * b.x; acc[0][1] += a0 * b.y; acc[0][2] += a0 * b.z; acc[0][3] += a0 * b.w;
            acc[1][0] += a1 * b.x; acc[1][1] += a1 * b.y; acc[1][2] += a1 * b.z; acc[1][3] += a1 * b.w;
            acc[2][0] += a2 * b.x; acc[2][1] += a2 * b.y; acc[2][2] += a2 * b.z; acc[2][3] += a2 * b.w;
            acc[3][0] += a3 * b.x; acc[3][1] += a3 * b.y; acc[3][2] += a3 * b.z; acc[3][3] += a3 * b.w;
        }
        __syncthreads();
    }

#pragma unroll
    for (int i = 0; i < 4; ++i) {
        int r = ty * 4 + i;
        int row = brow + r;
#pragma unroll
        for (int j = 0; j < 4; ++j) {
            int col = tx * 4 + j;
            float v = acc[i][j] + ((col < 32) ? mub[col] : lvb[col - 32]);
            Tile[r][col] = v;
            if (col < 32) mu_out[row * 32 + col] = v;
            else          lv_out[row * 32 + (col - 32)] = v;
        }
    }
    __syncthreads();
    for (int idx = tid; idx < 64 * 32; idx += 256) {
        int r = idx >> 5, l = idx & 31;
        float mu = Tile[r][l];
        float lv = Tile[r][32 + l];
        int row = brow + r;
        z_out[row * 32 + l] = mu + eps[row * 32 + l] * expf(0.5f * lv);
    }
}

__global__ __launch_bounds__(256) void gate_kernel(
    const float* __restrict__ z, const float* __restrict__ c,
    const float* __restrict__ g0w, const float* __restrict__ g0b,
    const float* __restrict__ g1w, const float* __restrict__ g1b,
    const float* __restrict__ g2w, const float* __restrict__ g2b,
    float* __restrict__ coef)
{
    __shared__ float W0[NIN * NGH];
    __shared__ float W1[NGH * NGH];
    __shared__ float W2[NGH * NE];
    __shared__ float B0[NGH], B1[NGH], B2[NE];
    __shared__ float GIN[8][204];

    const int tid = threadIdx.x;
    for (int i = tid; i < NIN * NGH; i += 256) W0[i] = g0w[i];
    for (int i = tid; i < NGH * NGH; i += 256) W1[i] = g1w[i];
    for (int i = tid; i < NGH * NE;  i += 256) W2[i] = g2w[i];
    if (tid < NGH) { B0[tid] = g0b[tid]; B1[tid] = g1b[tid]; }
    if (tid < NE)  { B2[tid] = g2b[tid]; }

    const int row0 = blockIdx.x * 8;
    for (int idx = tid; idx < 8 * NIN; idx += 256) {
        int rr = idx / NIN, i = idx - rr * NIN;
        GIN[rr][i] = (i < 32) ? z[(row0 + rr) * 32 + i]
                              : c[(row0 + rr) * 171 + (i - 32)];
    }
    __syncthreads();

    const int wave = tid >> 6, lane = tid & 63;
#pragma unroll
    for (int rw = 0; rw < 2; ++rw) {
        int rr = wave * 2 + rw;
        int row = row0 + rr;
        float a = B0[lane];
        for (int k = 0; k < NIN; ++k) a += GIN[rr][k] * W0[k * NGH + lane];
        float h = elu_f(a);
        float a1 = B1[lane];
#pragma unroll
        for (int k = 0; k < NGH; ++k) a1 += __shfl(h, k, 64) * W1[k * NGH + lane];
        float h2 = elu_f(a1);
        int o = lane & 15;
        float a2 = B2[o];
#pragma unroll
        for (int k = 0; k < NGH; ++k) a2 += __shfl(h2, k, 64) * W2[k * NE + o];
        float m = a2;
        for (int off = 1; off < 16; off <<= 1) m = fmaxf(m, __shfl_xor(m, off, 16));
        float ev = expf(a2 - m);
        float s = ev;
        for (int off = 1; off < 16; off <<= 1) s += __shfl_xor(s, off, 16);
        if (lane < 16) coef[row * 16 + lane] = ev / s;
    }
}

// ---------------------------------------------------------------------------
// convW: W [16][K][O] f32  ->  Wt [16][OP][KP] bf16 (transposed, zero-padded)
// grid (OP/32, KP/32, 16), 256 threads, 32x32 LDS transpose tile
// ---------------------------------------------------------------------------
__global__ __launch_bounds__(256) void convW(
    const float* __restrict__ W, int K, int O,
    short* __restrict__ Wt, int KP, int OP)
{
    __shared__ float T[32][33];
    const int e = blockIdx.z, ox = blockIdx.x, ky = blockIdx.y;
    const int c = threadIdx.x & 31, r0 = threadIdx.x >> 5;
#pragma unroll
    for (int i = 0; i < 4; ++i) {
        int r = r0 + i * 8;
        int gk = ky * 32 + r, go = ox * 32 + c;
        T[r][c] = (gk < K && go < O) ? W[((size_t)e * K + gk) * O + go] : 0.0f;
    }
    __syncthreads();
#pragma unroll
    for (int i = 0; i < 4; ++i) {
        int r = r0 + i * 8;
        int go = ox * 32 + r, gk = ky * 32 + c;
        Wt[((size_t)e * OP + go) * KP + gk] = f2bf(T[c][r]);
    }
}

// ---------------------------------------------------------------------------
// prep_inp: build bf16 A-panels.
// inp0[2048][224] = [z(32) | c(171) | 0]; inp1/inp2 [2048][288] z-part only.
// grid 2048 x 256
// ---------------------------------------------------------------------------
__global__ __launch_bounds__(256) void prep_inp(
    const float* __restrict__ z, const float* __restrict__ c,
    short* __restrict__ inp0, short* __restrict__ inp1, short* __restrict__ inp2)
{
    int idx = blockIdx.x * 256 + threadIdx.x;
    int b = idx >> 8, k = idx & 255;
    if (k < 224) {
        float v = (k < 32) ? z[b * 32 + k] : ((k < 203) ? c[b * 171 + (k - 32)] : 0.0f);
        inp0[b * 224 + k] = f2bf(v);
    } else {
        int j = k - 224;
        short v = f2bf(z[b * 32 + j]);
        inp1[b * 288 + j] = v;
        inp2[b * 288 + j] = v;
    }
}

// ---------------------------------------------------------------------------
// moe_gemm: partial[kg][b][o] = sum_{e in group kg} coef[b,e] * (inp[b,:] @ W[e,:,o])
// inp  : [2048][KP] bf16 (A panel, staged whole into LDS via global_load_lds)
// Wt   : [16][OP][KP] bf16 (B^T layout, k-contiguous)
// Tiles: BM=64, BN=64, BK=32; 4 waves 2x2; per-wave 2x2 16x16x32 MFMA frags.
// XOR pre-swizzle on global source (LDS linear) to kill ds_read_b128 conflicts.
// grid (OP/64, 32, 4)
// ---------------------------------------------------------------------------
template<int KP, int OP>
__global__ __launch_bounds__(256, 2) void moe_gemm(
    const short* __restrict__ inp,
    const short* __restrict__ Wt,
    const float* __restrict__ coef,
    float* __restrict__ partial)
{
    constexpr int NKS = KP / 32;   // K-steps per expert
    constexpr int CHR = KP / 8;    // 8-elem chunks per A row
    constexpr int EPG = 4;         // experts per group

    __shared__ short As[64 * KP];
    __shared__ short Bs[2][64 * 32];
    __shared__ float Cs[64][16];

    const int tid = threadIdx.x;
    const int lane = tid & 63;
    const int wid = tid >> 6;
    const int wm = wid >> 1, wn = wid & 1;
    const int bn = blockIdx.x, bm = blockIdx.y, kg = blockIdx.z;
    const int brow = bm * 64, bcol = bn * 64;
    const int wbase = wid * 1024;          // per-wave LDS byte base (64 lanes * 16B)
    const int kseg = lane >> 4;            // 0..3

    // ---- stage A panel (whole block-row, all K), swizzled source ----
#pragma unroll
    for (int i = 0; i < (64 * KP / 8) / 256; ++i) {
        int ch = i * 256 + tid;
        int r = ch / CHR, kc = ch - r * CHR;
        int kcs = kc ^ ((r >> 1) & 3);
        gload16((char*)As + i * 4096 + wbase,
                inp + (size_t)(brow + r) * KP + kcs * 8);
    }
    // ---- stage coef tile [64][16] ----
    {
        int r = tid >> 2, q = tid & 3;
        float4 v = ((const float4*)(coef + (size_t)(brow + r) * 16))[q];
        *(float4*)&Cs[r][q * 4] = v;
    }
    // ---- B staging helper (double-buffered), swizzled source ----
    auto stageB = [&](int buf, int s) {
        int ei = s / NKS, ks = s - ei * NKS;
        int e = kg * EPG + ei;
        int o = tid >> 2, sl = tid & 3;
        int sp = sl ^ ((o >> 1) & 3);
        gload16((char*)Bs[buf] + wbase,
                Wt + (size_t)(e * OP + bcol + o) * KP + ks * 32 + sp * 8);
    };
    stageB(0, 0);
    __syncthreads();

    const f32x4 zero4 = {0.0f, 0.0f, 0.0f, 0.0f};
    f32x4 outacc[2][2] = {{zero4, zero4}, {zero4, zero4}};
    f32x4 acc[2][2];
    int cur = 0;

    for (int s = 0; s < EPG * NKS; ++s) {
        int ei = s / NKS, ks = s - ei * NKS;
        if (ks == 0) {
            acc[0][0] = zero4; acc[0][1] = zero4;
            acc[1][0] = zero4; acc[1][1] = zero4;
        }
        if (s + 1 < EPG * NKS) stageB(cur ^ 1, s + 1);

        bf16x8 a[2], b[2];
#pragma unroll
        for (int mr = 0; mr < 2; ++mr) {
            int rr = wm * 32 + mr * 16 + (lane & 15);
            int kcr = ks * 4 + kseg;
            int kcp = kcr ^ ((rr >> 1) & 3);
            a[mr] = *(const bf16x8*)&As[rr * KP + kcp * 8];
        }
#pragma unroll
        for (int nr = 0; nr < 2; ++nr) {
            int oo = wn * 32 + nr * 16 + (lane & 15);
            int sp = kseg ^ ((oo >> 1) & 3);
            b[nr] = *(const bf16x8*)&Bs[cur][oo * 32 + sp * 8];
        }
#pragma unroll
        for (int mr = 0; mr < 2; ++mr)
#pragma unroll
            for (int nr = 0; nr < 2; ++nr)
                acc[mr][nr] = __builtin_amdgcn_mfma_f32_16x16x32_bf16(
                    a[mr], b[nr], acc[mr][nr], 0, 0, 0);

        if (ks == NKS - 1) {
            int e = kg * EPG + ei;
#pragma unroll
            for (int mr = 0; mr < 2; ++mr) {
                int rb = wm * 32 + mr * 16 + kseg * 4;
#pragma unroll
                for (int j = 0; j < 4; ++j) {
                    float cfv = Cs[rb + j][e];
#pragma unroll
                    for (int nr = 0; nr < 2; ++nr)
                        outacc[mr][nr][j] += cfv * acc[mr][nr][j];
                }
            }
        }
        __syncthreads();
        cur ^= 1;
    }

    float* pout = partial + (size_t)kg * 2048 * OP;
#pragma unroll
    for (int mr = 0; mr < 2; ++mr)
#pragma unroll
        for (int j = 0; j < 4; ++j) {
            int row = brow + wm * 32 + mr * 16 + kseg * 4 + j;
#pragma unroll
            for (int nr = 0; nr < 2; ++nr) {
                int col = bcol + wn * 32 + nr * 16 + (lane & 15);
                pout[(size_t)row * OP + col] = outacc[mr][nr][j];
            }
        }
}

// ---------------------------------------------------------------------------
// moe_finish: v = sum_kg partial + coef@bb ; act; write bf16 next-panel or f32 out
// grid 256 blocks x 8 rows
// ---------------------------------------------------------------------------
template<int NP, int O, bool ACT>
__global__ __launch_bounds__(256) void moe_finish(
    const float* __restrict__ partial,
    const float* __restrict__ coef,
    const float* __restrict__ bb,
    short* __restrict__ nxt,      // bf16 dst ([2048][288], cols 32..) or null
    float* __restrict__ fout)     // f32 dst [2048][O] or null
{
    __shared__ float bbs[16 * O];
    __shared__ float cfs[8][16];
    const int tid = threadIdx.x;
    const int row0 = blockIdx.x * 8;

    for (int i = tid; i < 16 * O; i += 256) bbs[i] = bb[i];
    if (tid < 128) cfs[tid >> 4][tid & 15] = coef[(row0 + (tid >> 4)) * 16 + (tid & 15)];
    __syncthreads();

    for (int idx = tid; idx < 8 * NP; idx += 256) {
        int r = idx / NP, o = idx - r * NP;
        if (o < O) {
            int row = row0 + r;
            float v = partial[(size_t)row * NP + o]
                    + partial[(size_t)(2048 + row) * NP + o]
                    + partial[(size_t)(4096 + row) * NP + o]
                    + partial[(size_t)(6144 + row) * NP + o];
            float bias = 0.0f;
#pragma unroll
            for (int e = 0; e < 16; ++e) bias += cfs[r][e] * bbs[e * O + o];
            v += bias;
            if (ACT) v = elu_f(v);
            if (nxt) nxt[(size_t)row * 288 + 32 + o] = f2bf(v);
            else     fout[(size_t)row * O + o] = v;
        }
    }
}

// ---------------------------------------------------------------------------
extern "C" void kernel_launch(void* const* d_in, const int* in_sizes, int n_in,
                              void* d_out, int out_size, void* d_ws, size_t ws_size,
                              hipStream_t stream)
{
    const float* x    = (const float*)d_in[0];
    const float* c    = (const float*)d_in[1];
    const float* eps  = (const float*)d_in[2];
    const float* fc1w = (const float*)d_in[3];
    const float* fc1b = (const float*)d_in[4];
    const float* fc2w = (const float*)d_in[5];
    const float* fc2b = (const float*)d_in[6];
    const float* muw  = (const float*)d_in[7];
    const float* mub  = (const float*)d_in[8];
    const float* lvw  = (const float*)d_in[9];
    const float* lvb  = (const float*)d_in[10];
    const float* g0w  = (const float*)d_in[11];
    const float* g0b  = (const float*)d_in[12];
    const float* g1w  = (const float*)d_in[13];
    const float* g1b  = (const float*)d_in[14];
    const float* g2w  = (const float*)d_in[15];
    const float* g2b  = (const float*)d_in[16];
    const float* w0   = (const float*)d_in[17];
    const float* b0   = (const float*)d_in[18];
    const float* w1   = (const float*)d_in[19];
    const float* b1   = (const float*)d_in[20];
    const float* w2   = (const float*)d_in[21];
    const float* b2   = (const float*)d_in[22];

    float* out       = (float*)d_out;
    float* out_layer = out;                       // [2048,171]
    float* out_mu    = out + NB * NOUT;           // [2048,32]
    float* out_lv    = out_mu + NB * NL;          // [2048,32]

    float* ws      = (float*)d_ws;
    float* h1      = ws;                          // 524288 f
    float* h2      = h1 + 524288;                 // 524288 f
    float* zb      = h2 + 524288;                 // 65536 f
    float* cf      = zb + 65536;                  // 32768 f
    float* partial = cf + 32768;                  // 4*2048*256 = 2097152 f
    short* inp0 = (short*)(partial + 2097152);    // 2048*224 bf16
    short* inp1 = inp0 + 2048 * 224;              // 2048*288
    short* inp2 = inp1 + 2048 * 288;              // 2048*288
    short* Wt0  = inp2 + 2048 * 288;              // 16*256*224
    short* Wt1  = Wt0 + 16 * 256 * 224;           // 16*256*288
    short* Wt2  = Wt1 + 16 * 256 * 288;           // 16*192*288

    dim3 blk(256);

    // Weight conversion/transposition (every call; deterministic)
    convW<<<dim3(8, 7, 16), blk, 0, stream>>>(w0, 203, 256, Wt0, 224, 256);
    convW<<<dim3(8, 9, 16), blk, 0, stream>>>(w1, 288, 256, Wt1, 288, 256);
    convW<<<dim3(6, 9, 16), blk, 0, stream>>>(w2, 288, 171, Wt2, 288, 192);

    // Encoder (f32, unchanged)
    gemm_cat_elu<<<dim3(4, 32), blk, 0, stream>>>(x, 171, 171, c, 171, 342, fc1w, 256, fc1b, h1);
    gemm_cat_elu<<<dim3(4, 32), blk, 0, stream>>>(x, 171, 171, h1, 256, 427, fc2w, 256, fc2b, h2);
    gemm_mulv<<<dim3(32), blk, 0, stream>>>(x, h2, muw, mub, lvw, lvb, eps, out_mu, out_lv, zb);
    gate_kernel<<<dim3(256), blk, 0, stream>>>(zb, c, g0w, g0b, g1w, g1b, g2w, g2b, cf);

    // Build bf16 A panels (z | c for layer0; z-part of layer1/2 panels)
    prep_inp<<<dim3(2048), blk, 0, stream>>>(zb, c, inp0, inp1, inp2);

    // MoE layer 0: K=224(pad of 203), O=256
    moe_gemm<224, 256><<<dim3(4, 32, 4), blk, 0, stream>>>(inp0, Wt0, cf, partial);
    moe_finish<256, 256, true><<<dim3(256), blk, 0, stream>>>(partial, cf, b0, inp1, nullptr);
    // MoE layer 1: K=288, O=256
    moe_gemm<288, 256><<<dim3(4, 32, 4), blk, 0, stream>>>(inp1, Wt1, cf, partial);
    moe_finish<256, 256, true><<<dim3(256), blk, 0, stream>>>(partial, cf, b1, inp2, nullptr);
    // MoE layer 2: K=288, O=192(pad of 171)
    moe_gemm<288, 192><<<dim3(3, 32, 4), blk, 0, stream>>>(inp2, Wt2, cf, partial);
    moe_finish<192, 171, false><<<dim3(256), blk, 0, stream>>>(partial, cf, b2, nullptr, out_layer);
}

// Round 3
// 140.530 us; speedup vs baseline: 10.2596x; 2.3596x over previous
//
#include <hip/hip_runtime.h>
#include <math.h>

// Problem constants
#define NB   2048
#define NFC  171
#define NFR  171
#define NL   32
#define NH   256
#define NE   16
#define NGH  64
#define NIN  203   /* L + FC */
#define NINT 288   /* L + H  */
#define NOUT 171

typedef __attribute__((ext_vector_type(8))) short bf16x8;   // 8 bf16 in 4 VGPRs
typedef __attribute__((ext_vector_type(4))) float f32x4;    // MFMA acc

__device__ __forceinline__ float elu_f(float v) {
    return v > 0.0f ? v : expm1f(v);
}

// f32 -> bf16 bits, round-to-nearest-even
__device__ __forceinline__ short f2bf(float f) {
    unsigned u = __float_as_uint(f);
    unsigned r = (u + 0x7FFFu + ((u >> 16) & 1u)) >> 16;
    return (short)r;
}
__device__ __forceinline__ float bf2f(short s) {
    return __uint_as_float(((unsigned)(unsigned short)s) << 16);
}

// async global->LDS, 16 bytes per lane; lds base must be wave-uniform
__device__ __forceinline__ void gload16(void* lds, const void* g) {
    __builtin_amdgcn_global_load_lds(
        (const __attribute__((address_space(1))) unsigned*)g,
        (__attribute__((address_space(3))) unsigned*)lds, 16, 0, 0);
}

// ---------------------------------------------------------------------------
// prepW: batched weight transpose+bf16.  All 7 segments in one launch.
// Each block handles one 32x32 tile: dst[(e*OP+o)*KP+k] = bf16(src[(e*K+k)*O+o])
// grid = 3140 blocks x 256
// ---------------------------------------------------------------------------
__global__ __launch_bounds__(256) void prepW(
    const float* s0, const float* s1, const float* s2, const float* s3,
    const float* s4, const float* s5, const float* s6,
    short* d0, short* d1, short* d2, short* d3,
    short* d4, short* d5, short* d6)
{
    constexpr int K_[7]   = {342, 427, 427, 427, 203, 288, 288};
    constexpr int O_[7]   = {256, 256,  32,  32, 256, 256, 171};
    constexpr int KP_[7]  = {352, 448, 448, 448, 224, 288, 288};
    constexpr int OP_[7]  = {256, 256,  64,  64, 256, 256, 192};
    constexpr int nKT_[7] = { 11,  14,  14,  14,   7,   9,   9};
    constexpr int tpe_[7] = { 88, 112,  14,  14,  56,  72,  54};
    constexpr int st_[7]  = {  0,  88, 200, 214, 228,1124,2276};
    const float* srcs[7] = {s0, s1, s2, s3, s4, s5, s6};
    short*       dsts[7] = {d0, d1, d2, d3, d4, d5, d6};

    __shared__ float T[32][33];
    int t = blockIdx.x;
    int s = 0;
    while (s < 6 && t >= st_[s + 1]) ++s;
    int local = t - st_[s];
    int e = local / tpe_[s];
    int rem = local - e * tpe_[s];
    int ox = rem / nKT_[s];
    int ky = rem - ox * nKT_[s];
    const int K = K_[s], O = O_[s], KP = KP_[s], OP = OP_[s];
    const float* src = srcs[s];
    short* dst = dsts[s];

    const int cc = threadIdx.x & 31, r0 = threadIdx.x >> 5;
#pragma unroll
    for (int i = 0; i < 4; ++i) {
        int r = r0 + i * 8;
        int gk = ky * 32 + r, go = ox * 32 + cc;
        T[r][cc] = (gk < K && go < O) ? src[((size_t)e * K + gk) * O + go] : 0.0f;
    }
    __syncthreads();
#pragma unroll
    for (int i = 0; i < 4; ++i) {
        int r = r0 + i * 8;
        int go = ox * 32 + r, gk = ky * 32 + cc;
        dst[((size_t)e * OP + go) * KP + gk] = f2bf(T[cc][r]);
    }
}

// ---------------------------------------------------------------------------
// prepP: build bf16 A-panels from x, c (one block per batch row).
//  xc  [2048][352] = [x(171)|c(171)|0]
//  xh1 [2048][448] : x part (0..170) + zero pad (427..447); h1 by enc1
//  xh2 [2048][448] : same; h2 by enc2
//  inp0[2048][224] : c at cols 32..202, 0 at 203..223; z by mulvz
// ---------------------------------------------------------------------------
__global__ __launch_bounds__(256) void prepP(
    const float* __restrict__ x, const float* __restrict__ c,
    short* __restrict__ xc, short* __restrict__ xh1, short* __restrict__ xh2,
    short* __restrict__ inp0)
{
    const int b = blockIdx.x, tid = threadIdx.x;
    for (int i = tid; i < 352; i += 256) {
        float v = (i < 171) ? x[b * 171 + i] : ((i < 342) ? c[b * 171 + (i - 171)] : 0.0f);
        xc[(size_t)b * 352 + i] = f2bf(v);
    }
    for (int i = tid; i < 171; i += 256) {
        short v = f2bf(x[b * 171 + i]);
        xh1[(size_t)b * 448 + i] = v;
        xh2[(size_t)b * 448 + i] = v;
    }
    for (int i = tid; i < 21; i += 256) {
        xh1[(size_t)b * 448 + 427 + i] = 0;
        xh2[(size_t)b * 448 + 427 + i] = 0;
    }
    for (int i = tid; i < 192; i += 256) {
        inp0[(size_t)b * 224 + 32 + i] = (i < 171) ? f2bf(c[b * 171 + i]) : (short)0;
    }
}

// ---------------------------------------------------------------------------
// enc_gemm: dst[row][dstoff+col] = bf16(ELU(A[row,:] @ Wt[col,:] + bias[col]))
// A: [2048][KP] bf16; Wt: [NO][KP] bf16.  BM=64,BN=64, 4 waves 2x2 frags.
// grid (NO/64, 32)
// ---------------------------------------------------------------------------
template<int KP>
__global__ __launch_bounds__(256, 2) void enc_gemm(
    const short* __restrict__ A,
    const short* __restrict__ Wt,
    const float* __restrict__ bias,
    short* __restrict__ dst, int dstld, int dstoff)
{
    constexpr int NKS = KP / 32;
    constexpr int CHR = KP / 8;

    __shared__ short As[64 * KP];
    __shared__ short Bs[2][64 * 32];

    const int tid = threadIdx.x;
    const int lane = tid & 63;
    const int wid = tid >> 6;
    const int wm = wid >> 1, wn = wid & 1;
    const int brow = blockIdx.y * 64, bcol = blockIdx.x * 64;
    const int wbase = wid * 1024;
    const int kseg = lane >> 4;

#pragma unroll
    for (int i = 0; i < KP / 32; ++i) {
        int ch = i * 256 + tid;
        int r = ch / CHR, kc = ch - r * CHR;
        int kcs = kc ^ ((r >> 1) & 3);
        gload16((char*)As + i * 4096 + wbase, A + (size_t)(brow + r) * KP + kcs * 8);
    }
    auto stageB = [&](int buf, int ks) {
        int o = tid >> 2, sl = tid & 3;
        int sp = sl ^ ((o >> 1) & 3);
        gload16((char*)Bs[buf] + wbase,
                Wt + (size_t)(bcol + o) * KP + ks * 32 + sp * 8);
    };
    stageB(0, 0);
    __syncthreads();

    const f32x4 zero4 = {0.0f, 0.0f, 0.0f, 0.0f};
    f32x4 acc[2][2] = {{zero4, zero4}, {zero4, zero4}};
    int cur = 0;

    for (int s = 0; s < NKS; ++s) {
        if (s + 1 < NKS) stageB(cur ^ 1, s + 1);
        bf16x8 a[2], b[2];
#pragma unroll
        for (int mr = 0; mr < 2; ++mr) {
            int rr = wm * 32 + mr * 16 + (lane & 15);
            int kcr = s * 4 + kseg;
            int kcp = kcr ^ ((rr >> 1) & 3);
            a[mr] = *(const bf16x8*)&As[rr * KP + kcp * 8];
        }
#pragma unroll
        for (int nr = 0; nr < 2; ++nr) {
            int oo = wn * 32 + nr * 16 + (lane & 15);
            int sp = kseg ^ ((oo >> 1) & 3);
            b[nr] = *(const bf16x8*)&Bs[cur][oo * 32 + sp * 8];
        }
#pragma unroll
        for (int mr = 0; mr < 2; ++mr)
#pragma unroll
            for (int nr = 0; nr < 2; ++nr)
                acc[mr][nr] = __builtin_amdgcn_mfma_f32_16x16x32_bf16(
                    a[mr], b[nr], acc[mr][nr], 0, 0, 0);
        __syncthreads();
        cur ^= 1;
    }

#pragma unroll
    for (int mr = 0; mr < 2; ++mr)
#pragma unroll
        for (int j = 0; j < 4; ++j) {
            int row = brow + wm * 32 + mr * 16 + kseg * 4 + j;
#pragma unroll
            for (int nr = 0; nr < 2; ++nr) {
                int col = bcol + wn * 32 + nr * 16 + (lane & 15);
                float v = acc[mr][nr][j] + bias[col];
                dst[(size_t)row * dstld + dstoff + col] = f2bf(elu_f(v));
            }
        }
}

// ---------------------------------------------------------------------------
// mulvz: [mu|lv] = xh2 @ mlWt^T + bias;  mu,lv -> d_out (f32);
//        z = mu + eps*exp(0.5*lv) -> bf16 into inp0/inp1/inp2 cols 0..31.
// mlWt: [64][448] (rows 0-31 mu, 32-63 lv). grid (1, 32).
// Wave-cols: wn=0 holds mu cols, wn=1 holds lv cols; LDS exchange for z.
// ---------------------------------------------------------------------------
__global__ __launch_bounds__(256, 2) void mulvz(
    const short* __restrict__ A,             // xh2 [2048][448]
    const short* __restrict__ Wt,            // [64][448]
    const float* __restrict__ mub, const float* __restrict__ lvb,
    const float* __restrict__ eps,
    float* __restrict__ mu_out, float* __restrict__ lv_out,
    short* __restrict__ inp0, short* __restrict__ inp1, short* __restrict__ inp2)
{
    constexpr int KP = 448;
    constexpr int NKS = KP / 32;
    constexpr int CHR = KP / 8;

    __shared__ short As[64 * KP];
    __shared__ short Bs[2][64 * 32];
    __shared__ float Els[64][32];

    const int tid = threadIdx.x;
    const int lane = tid & 63;
    const int wid = tid >> 6;
    const int wm = wid >> 1, wn = wid & 1;
    const int brow = blockIdx.y * 64;
    const int wbase = wid * 1024;
    const int kseg = lane >> 4;

#pragma unroll
    for (int i = 0; i < KP / 32; ++i) {
        int ch = i * 256 + tid;
        int r = ch / CHR, kc = ch - r * CHR;
        int kcs = kc ^ ((r >> 1) & 3);
        gload16((char*)As + i * 4096 + wbase, A + (size_t)(brow + r) * KP + kcs * 8);
    }
    auto stageB = [&](int buf, int ks) {
        int o = tid >> 2, sl = tid & 3;
        int sp = sl ^ ((o >> 1) & 3);
        gload16((char*)Bs[buf] + wbase,
                Wt + (size_t)o * KP + ks * 32 + sp * 8);
    };
    stageB(0, 0);
    __syncthreads();

    const f32x4 zero4 = {0.0f, 0.0f, 0.0f, 0.0f};
    f32x4 acc[2][2] = {{zero4, zero4}, {zero4, zero4}};
    int cur = 0;

    for (int s = 0; s < NKS; ++s) {
        if (s + 1 < NKS) stageB(cur ^ 1, s + 1);
        bf16x8 a[2], b[2];
#pragma unroll
        for (int mr = 0; mr < 2; ++mr) {
            int rr = wm * 32 + mr * 16 + (lane & 15);
            int kcr = s * 4 + kseg;
            int kcp = kcr ^ ((rr >> 1) & 3);
            a[mr] = *(const bf16x8*)&As[rr * KP + kcp * 8];
        }
#pragma unroll
        for (int nr = 0; nr < 2; ++nr) {
            int oo = wn * 32 + nr * 16 + (lane & 15);
            int sp = kseg ^ ((oo >> 1) & 3);
            b[nr] = *(const bf16x8*)&Bs[cur][oo * 32 + sp * 8];
        }
#pragma unroll
        for (int mr = 0; mr < 2; ++mr)
#pragma unroll
            for (int nr = 0; nr < 2; ++nr)
                acc[mr][nr] = __builtin_amdgcn_mfma_f32_16x16x32_bf16(
                    a[mr], b[nr], acc[mr][nr], 0, 0, 0);
        __syncthreads();
        cur ^= 1;
    }

    // epilogue: wn=0 -> mu cols (0..31); wn=1 -> lv cols (0..31 of lv)
#pragma unroll
    for (int mr = 0; mr < 2; ++mr)
#pragma unroll
        for (int j = 0; j < 4; ++j) {
            int rl = wm * 32 + mr * 16 + kseg * 4 + j;
            int row = brow + rl;
#pragma unroll
            for (int nr = 0; nr < 2; ++nr) {
                int cc = nr * 16 + (lane & 15);      // 0..31
                if (wn == 1) {
                    float v = acc[mr][nr][j] + lvb[cc];
                    lv_out[(size_t)row * 32 + cc] = v;
                    Els[rl][cc] = expf(0.5f * v);
                } else {
                    float v = acc[mr][nr][j] + mub[cc];
                    mu_out[(size_t)row * 32 + cc] = v;
                    acc[mr][nr][j] = v;              // keep for z
                }
            }
        }
    __syncthreads();
    if (wn == 0) {
#pragma unroll
        for (int mr = 0; mr < 2; ++mr)
#pragma unroll
            for (int j = 0; j < 4; ++j) {
                int rl = wm * 32 + mr * 16 + kseg * 4 + j;
                int row = brow + rl;
#pragma unroll
                for (int nr = 0; nr < 2; ++nr) {
                    int cc = nr * 16 + (lane & 15);
                    float z = acc[mr][nr][j] + eps[(size_t)row * 32 + cc] * Els[rl][cc];
                    short zb = f2bf(z);
                    inp0[(size_t)row * 224 + cc] = zb;
                    inp1[(size_t)row * 288 + cc] = zb;
                    inp2[(size_t)row * 288 + cc] = zb;
                }
            }
    }
}

// ---------------------------------------------------------------------------
// Gate MLP + softmax -> coef [2048,16].  Reads bf16 [z|c] from inp0.
// ---------------------------------------------------------------------------
__global__ __launch_bounds__(256) void gate_kernel(
    const short* __restrict__ inp0,
    const float* __restrict__ g0w, const float* __restrict__ g0b,
    const float* __restrict__ g1w, const float* __restrict__ g1b,
    const float* __restrict__ g2w, const float* __restrict__ g2b,
    float* __restrict__ coef)
{
    __shared__ float W0[NIN * NGH];
    __shared__ float W1[NGH * NGH];
    __shared__ float W2[NGH * NE];
    __shared__ float B0[NGH], B1[NGH], B2[NE];
    __shared__ float GIN[8][204];

    const int tid = threadIdx.x;
    for (int i = tid; i < NIN * NGH; i += 256) W0[i] = g0w[i];
    for (int i = tid; i < NGH * NGH; i += 256) W1[i] = g1w[i];
    for (int i = tid; i < NGH * NE;  i += 256) W2[i] = g2w[i];
    if (tid < NGH) { B0[tid] = g0b[tid]; B1[tid] = g1b[tid]; }
    if (tid < NE)  { B2[tid] = g2b[tid]; }

    const int row0 = blockIdx.x * 8;
    for (int idx = tid; idx < 8 * NIN; idx += 256) {
        int rr = idx / NIN, i = idx - rr * NIN;
        GIN[rr][i] = bf2f(inp0[(size_t)(row0 + rr) * 224 + i]);
    }
    __syncthreads();

    const int wave = tid >> 6, lane = tid & 63;
#pragma unroll
    for (int rw = 0; rw < 2; ++rw) {
        int rr = wave * 2 + rw;
        int row = row0 + rr;
        float a = B0[lane];
        for (int k = 0; k < NIN; ++k) a += GIN[rr][k] * W0[k * NGH + lane];
        float h = elu_f(a);
        float a1 = B1[lane];
#pragma unroll
        for (int k = 0; k < NGH; ++k) a1 += __shfl(h, k, 64) * W1[k * NGH + lane];
        float h2 = elu_f(a1);
        int o = lane & 15;
        float a2 = B2[o];
#pragma unroll
        for (int k = 0; k < NGH; ++k) a2 += __shfl(h2, k, 64) * W2[k * NE + o];
        float m = a2;
        for (int off = 1; off < 16; off <<= 1) m = fmaxf(m, __shfl_xor(m, off, 16));
        float ev = expf(a2 - m);
        float s = ev;
        for (int off = 1; off < 16; off <<= 1) s += __shfl_xor(s, off, 16);
        if (lane < 16) coef[row * 16 + lane] = ev / s;
    }
}

// ---------------------------------------------------------------------------
// moe_gemm (unchanged structure from round 2 — verified)
// grid (OP/64, 32, 4)
// ---------------------------------------------------------------------------
template<int KP, int OP>
__global__ __launch_bounds__(256, 2) void moe_gemm(
    const short* __restrict__ inp,
    const short* __restrict__ Wt,
    const float* __restrict__ coef,
    float* __restrict__ partial)
{
    constexpr int NKS = KP / 32;
    constexpr int CHR = KP / 8;
    constexpr int EPG = 4;

    __shared__ short As[64 * KP];
    __shared__ short Bs[2][64 * 32];
    __shared__ float Cs[64][16];

    const int tid = threadIdx.x;
    const int lane = tid & 63;
    const int wid = tid >> 6;
    const int wm = wid >> 1, wn = wid & 1;
    const int bn = blockIdx.x, bm = blockIdx.y, kg = blockIdx.z;
    const int brow = bm * 64, bcol = bn * 64;
    const int wbase = wid * 1024;
    const int kseg = lane >> 4;

#pragma unroll
    for (int i = 0; i < (64 * KP / 8) / 256; ++i) {
        int ch = i * 256 + tid;
        int r = ch / CHR, kc = ch - r * CHR;
        int kcs = kc ^ ((r >> 1) & 3);
        gload16((char*)As + i * 4096 + wbase,
                inp + (size_t)(brow + r) * KP + kcs * 8);
    }
    {
        int r = tid >> 2, q = tid & 3;
        float4 v = ((const float4*)(coef + (size_t)(brow + r) * 16))[q];
        *(float4*)&Cs[r][q * 4] = v;
    }
    auto stageB = [&](int buf, int s) {
        int ei = s / NKS, ks = s - ei * NKS;
        int e = kg * EPG + ei;
        int o = tid >> 2, sl = tid & 3;
        int sp = sl ^ ((o >> 1) & 3);
        gload16((char*)Bs[buf] + wbase,
                Wt + (size_t)(e * OP + bcol + o) * KP + ks * 32 + sp * 8);
    };
    stageB(0, 0);
    __syncthreads();

    const f32x4 zero4 = {0.0f, 0.0f, 0.0f, 0.0f};
    f32x4 outacc[2][2] = {{zero4, zero4}, {zero4, zero4}};
    f32x4 acc[2][2];
    int cur = 0;

    for (int s = 0; s < EPG * NKS; ++s) {
        int ei = s / NKS, ks = s - ei * NKS;
        if (ks == 0) {
            acc[0][0] = zero4; acc[0][1] = zero4;
            acc[1][0] = zero4; acc[1][1] = zero4;
        }
        if (s + 1 < EPG * NKS) stageB(cur ^ 1, s + 1);

        bf16x8 a[2], b[2];
#pragma unroll
        for (int mr = 0; mr < 2; ++mr) {
            int rr = wm * 32 + mr * 16 + (lane & 15);
            int kcr = ks * 4 + kseg;
            int kcp = kcr ^ ((rr >> 1) & 3);
            a[mr] = *(const bf16x8*)&As[rr * KP + kcp * 8];
        }
#pragma unroll
        for (int nr = 0; nr < 2; ++nr) {
            int oo = wn * 32 + nr * 16 + (lane & 15);
            int sp = kseg ^ ((oo >> 1) & 3);
            b[nr] = *(const bf16x8*)&Bs[cur][oo * 32 + sp * 8];
        }
#pragma unroll
        for (int mr = 0; mr < 2; ++mr)
#pragma unroll
            for (int nr = 0; nr < 2; ++nr)
                acc[mr][nr] = __builtin_amdgcn_mfma_f32_16x16x32_bf16(
                    a[mr], b[nr], acc[mr][nr], 0, 0, 0);

        if (ks == NKS - 1) {
            int e = kg * EPG + ei;
#pragma unroll
            for (int mr = 0; mr < 2; ++mr) {
                int rb = wm * 32 + mr * 16 + kseg * 4;
#pragma unroll
                for (int j = 0; j < 4; ++j) {
                    float cfv = Cs[rb + j][e];
#pragma unroll
                    for (int nr = 0; nr < 2; ++nr)
                        outacc[mr][nr][j] += cfv * acc[mr][nr][j];
                }
            }
        }
        __syncthreads();
        cur ^= 1;
    }

    float* pout = partial + (size_t)kg * 2048 * OP;
#pragma unroll
    for (int mr = 0; mr < 2; ++mr)
#pragma unroll
        for (int j = 0; j < 4; ++j) {
            int row = brow + wm * 32 + mr * 16 + kseg * 4 + j;
#pragma unroll
            for (int nr = 0; nr < 2; ++nr) {
                int col = bcol + wn * 32 + nr * 16 + (lane & 15);
                pout[(size_t)row * OP + col] = outacc[mr][nr][j];
            }
        }
}

// ---------------------------------------------------------------------------
// moe_finish (unchanged from round 2)
// ---------------------------------------------------------------------------
template<int NP, int O, bool ACT>
__global__ __launch_bounds__(256) void moe_finish(
    const float* __restrict__ partial,
    const float* __restrict__ coef,
    const float* __restrict__ bb,
    short* __restrict__ nxt,
    float* __restrict__ fout)
{
    __shared__ float bbs[16 * O];
    __shared__ float cfs[8][16];
    const int tid = threadIdx.x;
    const int row0 = blockIdx.x * 8;

    for (int i = tid; i < 16 * O; i += 256) bbs[i] = bb[i];
    if (tid < 128) cfs[tid >> 4][tid & 15] = coef[(row0 + (tid >> 4)) * 16 + (tid & 15)];
    __syncthreads();

    for (int idx = tid; idx < 8 * NP; idx += 256) {
        int r = idx / NP, o = idx - r * NP;
        if (o < O) {
            int row = row0 + r;
            float v = partial[(size_t)row * NP + o]
                    + partial[(size_t)(2048 + row) * NP + o]
                    + partial[(size_t)(4096 + row) * NP + o]
                    + partial[(size_t)(6144 + row) * NP + o];
            float bias = 0.0f;
#pragma unroll
            for (int e = 0; e < 16; ++e) bias += cfs[r][e] * bbs[e * O + o];
            v += bias;
            if (ACT) v = elu_f(v);
            if (nxt) nxt[(size_t)row * 288 + 32 + o] = f2bf(v);
            else     fout[(size_t)row * O + o] = v;
        }
    }
}

// ---------------------------------------------------------------------------
extern "C" void kernel_launch(void* const* d_in, const int* in_sizes, int n_in,
                              void* d_out, int out_size, void* d_ws, size_t ws_size,
                              hipStream_t stream)
{
    const float* x    = (const float*)d_in[0];
    const float* c    = (const float*)d_in[1];
    const float* eps  = (const float*)d_in[2];
    const float* fc1w = (const float*)d_in[3];
    const float* fc1b = (const float*)d_in[4];
    const float* fc2w = (const float*)d_in[5];
    const float* fc2b = (const float*)d_in[6];
    const float* muw  = (const float*)d_in[7];
    const float* mub  = (const float*)d_in[8];
    const float* lvw  = (const float*)d_in[9];
    const float* lvb  = (const float*)d_in[10];
    const float* g0w  = (const float*)d_in[11];
    const float* g0b  = (const float*)d_in[12];
    const float* g1w  = (const float*)d_in[13];
    const float* g1b  = (const float*)d_in[14];
    const float* g2w  = (const float*)d_in[15];
    const float* g2b  = (const float*)d_in[16];
    const float* w0   = (const float*)d_in[17];
    const float* b0   = (const float*)d_in[18];
    const float* w1   = (const float*)d_in[19];
    const float* b1   = (const float*)d_in[20];
    const float* w2   = (const float*)d_in[21];
    const float* b2   = (const float*)d_in[22];

    float* out       = (float*)d_out;
    float* out_layer = out;                       // [2048,171]
    float* out_mu    = out + NB * NOUT;           // [2048,32]
    float* out_lv    = out_mu + NB * NL;          // [2048,32]

    float* ws      = (float*)d_ws;
    float* partial = ws;                          // 4*2048*256 f32
    float* cf      = partial + 2097152;           // 2048*16 f32
    short* xc    = (short*)(cf + 32768);          // 2048*352
    short* xh1   = xc   + (size_t)2048 * 352;     // 2048*448
    short* xh2   = xh1  + (size_t)2048 * 448;     // 2048*448
    short* inp0  = xh2  + (size_t)2048 * 448;     // 2048*224
    short* inp1  = inp0 + (size_t)2048 * 224;     // 2048*288
    short* inp2  = inp1 + (size_t)2048 * 288;     // 2048*288
    short* fc1Wt = inp2 + (size_t)2048 * 288;     // 256*352
    short* fc2Wt = fc1Wt + 256 * 352;             // 256*448
    short* mlWt  = fc2Wt + 256 * 448;             // 64*448
    short* Wt0   = mlWt + 64 * 448;               // 16*256*224
    short* Wt1   = Wt0 + 16 * 256 * 224;          // 16*256*288
    short* Wt2   = Wt1 + 16 * 256 * 288;          // 16*192*288

    dim3 blk(256);

    // all weight transposes in one launch
    prepW<<<dim3(3140), blk, 0, stream>>>(
        fc1w, fc2w, muw, lvw, w0, w1, w2,
        fc1Wt, fc2Wt, mlWt, mlWt + 32 * 448, Wt0, Wt1, Wt2);
    // bf16 input panels
    prepP<<<dim3(2048), blk, 0, stream>>>(x, c, xc, xh1, xh2, inp0);

    // encoder chain (bf16 MFMA)
    enc_gemm<352><<<dim3(4, 32), blk, 0, stream>>>(xc,  fc1Wt, fc1b, xh1, 448, 171);
    enc_gemm<448><<<dim3(4, 32), blk, 0, stream>>>(xh1, fc2Wt, fc2b, xh2, 448, 171);
    mulvz<<<dim3(1, 32), blk, 0, stream>>>(xh2, mlWt, mub, lvb, eps,
                                           out_mu, out_lv, inp0, inp1, inp2);
    gate_kernel<<<dim3(256), blk, 0, stream>>>(inp0, g0w, g0b, g1w, g1b, g2w, g2b, cf);

    // MoE layers
    moe_gemm<224, 256><<<dim3(4, 32, 4), blk, 0, stream>>>(inp0, Wt0, cf, partial);
    moe_finish<256, 256, true><<<dim3(256), blk, 0, stream>>>(partial, cf, b0, inp1, nullptr);
    moe_gemm<288, 256><<<dim3(4, 32, 4), blk, 0, stream>>>(inp1, Wt1, cf, partial);
    moe_finish<256, 256, true><<<dim3(256), blk, 0, stream>>>(partial, cf, b1, inp2, nullptr);
    moe_gemm<288, 192><<<dim3(3, 32, 4), blk, 0, stream>>>(inp2, Wt2, cf, partial);
    moe_finish<192, 171, false><<<dim3(256), blk, 0, stream>>>(partial, cf, b2, nullptr, out_layer);
}

// Round 4
// 126.537 us; speedup vs baseline: 11.3942x; 1.1106x over previous
//
#include <hip/hip_runtime.h>
#include <math.h>

// Problem constants
#define NB   2048
#define NFC  171
#define NFR  171
#define NL   32
#define NH   256
#define NE   16
#define NGH  64
#define NIN  203   /* L + FC */
#define NINT 288   /* L + H  */
#define NOUT 171

typedef __attribute__((ext_vector_type(8))) short bf16x8;   // 8 bf16 in 4 VGPRs
typedef __attribute__((ext_vector_type(4))) float f32x4;    // MFMA acc

__device__ __forceinline__ float elu_f(float v) {
    return v > 0.0f ? v : expm1f(v);
}

// f32 -> bf16 bits, round-to-nearest-even
__device__ __forceinline__ short f2bf(float f) {
    unsigned u = __float_as_uint(f);
    unsigned r = (u + 0x7FFFu + ((u >> 16) & 1u)) >> 16;
    return (short)r;
}
__device__ __forceinline__ float bf2f(short s) {
    return __uint_as_float(((unsigned)(unsigned short)s) << 16);
}

// async global->LDS, 16 bytes per lane; lds base must be wave-uniform
__device__ __forceinline__ void gload16(void* lds, const void* g) {
    __builtin_amdgcn_global_load_lds(
        (const __attribute__((address_space(1))) unsigned*)g,
        (__attribute__((address_space(3))) unsigned*)lds, 16, 0, 0);
}

// counted waitcnt (vm + all lgkm), then raw barrier done by caller
template<int N> __device__ __forceinline__ void waitcnt_vm() {
    if constexpr (N == 0)      asm volatile("s_waitcnt vmcnt(0) lgkmcnt(0)" ::: "memory");
    else if constexpr (N == 1) asm volatile("s_waitcnt vmcnt(1) lgkmcnt(0)" ::: "memory");
    else                       asm volatile("s_waitcnt vmcnt(2) lgkmcnt(0)" ::: "memory");
}
__device__ __forceinline__ void loop_sync(int s, int NS) {
    if (s + 3 < NS)      waitcnt_vm<2>();
    else if (s + 2 < NS) waitcnt_vm<1>();
    else                 waitcnt_vm<0>();
    __builtin_amdgcn_s_barrier();
}

// ---------------------------------------------------------------------------
// prep_all: blocks [0,3140) = weight transpose tiles; [3140, 3140+2048) = input panels
// ---------------------------------------------------------------------------
__global__ __launch_bounds__(256) void prep_all(
    const float* s0, const float* s1, const float* s2, const float* s3,
    const float* s4, const float* s5, const float* s6,
    short* d0, short* d1, short* d2, short* d3,
    short* d4, short* d5, short* d6,
    const float* __restrict__ x, const float* __restrict__ c,
    short* __restrict__ xc, short* __restrict__ xh1, short* __restrict__ xh2,
    short* __restrict__ inp0)
{
    __shared__ float T[32][33];
    const int tid = threadIdx.x;

    if (blockIdx.x >= 3140) {
        // ---- input panels, one block per batch row ----
        const int b = blockIdx.x - 3140;
        for (int i = tid; i < 352; i += 256) {
            float v = (i < 171) ? x[b * 171 + i] : ((i < 342) ? c[b * 171 + (i - 171)] : 0.0f);
            xc[(size_t)b * 352 + i] = f2bf(v);
        }
        for (int i = tid; i < 171; i += 256) {
            short v = f2bf(x[b * 171 + i]);
            xh1[(size_t)b * 448 + i] = v;
            xh2[(size_t)b * 448 + i] = v;
        }
        for (int i = tid; i < 21; i += 256) {
            xh1[(size_t)b * 448 + 427 + i] = 0;
            xh2[(size_t)b * 448 + 427 + i] = 0;
        }
        for (int i = tid; i < 192; i += 256) {
            inp0[(size_t)b * 224 + 32 + i] = (i < 171) ? f2bf(c[b * 171 + i]) : (short)0;
        }
        return;
    }

    // ---- weight transpose tiles ----
    constexpr int K_[7]   = {342, 427, 427, 427, 203, 288, 288};
    constexpr int O_[7]   = {256, 256,  32,  32, 256, 256, 171};
    constexpr int KP_[7]  = {352, 448, 448, 448, 224, 288, 288};
    constexpr int OP_[7]  = {256, 256,  64,  64, 256, 256, 192};
    constexpr int nKT_[7] = { 11,  14,  14,  14,   7,   9,   9};
    constexpr int tpe_[7] = { 88, 112,  14,  14,  56,  72,  54};
    constexpr int st_[7]  = {  0,  88, 200, 214, 228,1124,2276};
    const float* srcs[7] = {s0, s1, s2, s3, s4, s5, s6};
    short*       dsts[7] = {d0, d1, d2, d3, d4, d5, d6};

    int t = blockIdx.x;
    int s = 0;
    while (s < 6 && t >= st_[s + 1]) ++s;
    int local = t - st_[s];
    int e = local / tpe_[s];
    int rem = local - e * tpe_[s];
    int ox = rem / nKT_[s];
    int ky = rem - ox * nKT_[s];
    const int K = K_[s], O = O_[s], KP = KP_[s], OP = OP_[s];
    const float* src = srcs[s];
    short* dst = dsts[s];

    const int cc = tid & 31, r0 = tid >> 5;
#pragma unroll
    for (int i = 0; i < 4; ++i) {
        int r = r0 + i * 8;
        int gk = ky * 32 + r, go = ox * 32 + cc;
        T[r][cc] = (gk < K && go < O) ? src[((size_t)e * K + gk) * O + go] : 0.0f;
    }
    __syncthreads();
#pragma unroll
    for (int i = 0; i < 4; ++i) {
        int r = r0 + i * 8;
        int go = ox * 32 + r, gk = ky * 32 + cc;
        dst[((size_t)e * OP + go) * KP + gk] = f2bf(T[cc][r]);
    }
}

// ---------------------------------------------------------------------------
// enc_gemm: dst[row][dstoff+col] = bf16(ELU(A[row,:] @ Wt[col,:] + bias[col]))
// Depth-3 B prefetch, counted vmcnt, raw barriers.  grid (NO/64, 32)
// ---------------------------------------------------------------------------
template<int KP>
__global__ __launch_bounds__(256, 2) void enc_gemm(
    const short* __restrict__ A,
    const short* __restrict__ Wt,
    const float* __restrict__ bias,
    short* __restrict__ dst, int dstld, int dstoff)
{
    constexpr int NKS = KP / 32;
    constexpr int CHR = KP / 8;

    __shared__ short As[64 * KP];
    __shared__ short Bs[4][64 * 32];

    const int tid = threadIdx.x;
    const int lane = tid & 63;
    const int wid = tid >> 6;
    const int wm = wid >> 1, wn = wid & 1;
    const int brow = blockIdx.y * 64, bcol = blockIdx.x * 64;
    const int wbase = wid * 1024;
    const int kseg = lane >> 4;

#pragma unroll
    for (int i = 0; i < KP / 32; ++i) {
        int ch = i * 256 + tid;
        int r = ch / CHR, kc = ch - r * CHR;
        int kcs = kc ^ ((r >> 1) & 3);
        gload16((char*)As + i * 4096 + wbase, A + (size_t)(brow + r) * KP + kcs * 8);
    }
    auto stageB = [&](int buf, int ks) {
        int o = tid >> 2, sl = tid & 3;
        int sp = sl ^ ((o >> 1) & 3);
        gload16((char*)Bs[buf] + wbase,
                Wt + (size_t)(bcol + o) * KP + ks * 32 + sp * 8);
    };
    stageB(0, 0); stageB(1, 1); stageB(2, 2);
    waitcnt_vm<2>();
    __builtin_amdgcn_s_barrier();

    const f32x4 zero4 = {0.0f, 0.0f, 0.0f, 0.0f};
    f32x4 acc[2][2] = {{zero4, zero4}, {zero4, zero4}};

    for (int s = 0; s < NKS; ++s) {
        if (s + 3 < NKS) stageB((s + 3) & 3, s + 3);
        bf16x8 a[2], b[2];
#pragma unroll
        for (int mr = 0; mr < 2; ++mr) {
            int rr = wm * 32 + mr * 16 + (lane & 15);
            int kcr = s * 4 + kseg;
            int kcp = kcr ^ ((rr >> 1) & 3);
            a[mr] = *(const bf16x8*)&As[rr * KP + kcp * 8];
        }
#pragma unroll
        for (int nr = 0; nr < 2; ++nr) {
            int oo = wn * 32 + nr * 16 + (lane & 15);
            int sp = kseg ^ ((oo >> 1) & 3);
            b[nr] = *(const bf16x8*)&Bs[s & 3][oo * 32 + sp * 8];
        }
#pragma unroll
        for (int mr = 0; mr < 2; ++mr)
#pragma unroll
            for (int nr = 0; nr < 2; ++nr)
                acc[mr][nr] = __builtin_amdgcn_mfma_f32_16x16x32_bf16(
                    a[mr], b[nr], acc[mr][nr], 0, 0, 0);
        loop_sync(s, NKS);
    }

#pragma unroll
    for (int mr = 0; mr < 2; ++mr)
#pragma unroll
        for (int j = 0; j < 4; ++j) {
            int row = brow + wm * 32 + mr * 16 + kseg * 4 + j;
#pragma unroll
            for (int nr = 0; nr < 2; ++nr) {
                int col = bcol + wn * 32 + nr * 16 + (lane & 15);
                float v = acc[mr][nr][j] + bias[col];
                dst[(size_t)row * dstld + dstoff + col] = f2bf(elu_f(v));
            }
        }
}

// ---------------------------------------------------------------------------
// mulvz: BM=32, grid (1,64).  [mu|lv] = xh2 @ mlWt^T + bias; z -> panels.
// Waves: wm=wid&1 (16-row half), wn=wid>>1 (32-col half: 0=mu, 1=lv).
// ---------------------------------------------------------------------------
__global__ __launch_bounds__(256, 2) void mulvz(
    const short* __restrict__ A,             // xh2 [2048][448]
    const short* __restrict__ Wt,            // [64][448]
    const float* __restrict__ mub, const float* __restrict__ lvb,
    const float* __restrict__ eps,
    float* __restrict__ mu_out, float* __restrict__ lv_out,
    short* __restrict__ inp0, short* __restrict__ inp1, short* __restrict__ inp2)
{
    constexpr int KP = 448;
    constexpr int NKS = KP / 32;
    constexpr int CHR = KP / 8;   // 56

    __shared__ short As[32 * KP];
    __shared__ short Bs[4][64 * 32];
    __shared__ float Els[32][32];

    const int tid = threadIdx.x;
    const int lane = tid & 63;
    const int wid = tid >> 6;
    const int wm = wid & 1, wn = wid >> 1;
    const int brow = blockIdx.y * 32;
    const int wbase = wid * 1024;
    const int kseg = lane >> 4;

#pragma unroll
    for (int i = 0; i < 7; ++i) {            // 32*448/8/256
        int ch = i * 256 + tid;
        int r = ch / CHR, kc = ch - r * CHR;
        int kcs = kc ^ ((r >> 1) & 3);
        gload16((char*)As + i * 4096 + wbase, A + (size_t)(brow + r) * KP + kcs * 8);
    }
    auto stageB = [&](int buf, int ks) {
        int o = tid >> 2, sl = tid & 3;
        int sp = sl ^ ((o >> 1) & 3);
        gload16((char*)Bs[buf] + wbase,
                Wt + (size_t)o * KP + ks * 32 + sp * 8);
    };
    stageB(0, 0); stageB(1, 1); stageB(2, 2);
    waitcnt_vm<2>();
    __builtin_amdgcn_s_barrier();

    const f32x4 zero4 = {0.0f, 0.0f, 0.0f, 0.0f};
    f32x4 acc[2] = {zero4, zero4};

    for (int s = 0; s < NKS; ++s) {
        if (s + 3 < NKS) stageB((s + 3) & 3, s + 3);
        bf16x8 a, b[2];
        {
            int rr = wm * 16 + (lane & 15);
            int kcr = s * 4 + kseg;
            int kcp = kcr ^ ((rr >> 1) & 3);
            a = *(const bf16x8*)&As[rr * KP + kcp * 8];
        }
#pragma unroll
        for (int nr = 0; nr < 2; ++nr) {
            int oo = wn * 32 + nr * 16 + (lane & 15);
            int sp = kseg ^ ((oo >> 1) & 3);
            b[nr] = *(const bf16x8*)&Bs[s & 3][oo * 32 + sp * 8];
        }
#pragma unroll
        for (int nr = 0; nr < 2; ++nr)
            acc[nr] = __builtin_amdgcn_mfma_f32_16x16x32_bf16(a, b[nr], acc[nr], 0, 0, 0);
        loop_sync(s, NKS);
    }

    // epilogue
#pragma unroll
    for (int j = 0; j < 4; ++j) {
        int rl = wm * 16 + kseg * 4 + j;
        int row = brow + rl;
#pragma unroll
        for (int nr = 0; nr < 2; ++nr) {
            int cc = nr * 16 + (lane & 15);      // 0..31
            if (wn == 1) {
                float v = acc[nr][j] + lvb[cc];
                lv_out[(size_t)row * 32 + cc] = v;
                Els[rl][cc] = expf(0.5f * v);
            } else {
                float v = acc[nr][j] + mub[cc];
                mu_out[(size_t)row * 32 + cc] = v;
                acc[nr][j] = v;
            }
        }
    }
    __syncthreads();
    if (wn == 0) {
#pragma unroll
        for (int j = 0; j < 4; ++j) {
            int rl = wm * 16 + kseg * 4 + j;
            int row = brow + rl;
#pragma unroll
            for (int nr = 0; nr < 2; ++nr) {
                int cc = nr * 16 + (lane & 15);
                float z = acc[nr][j] + eps[(size_t)row * 32 + cc] * Els[rl][cc];
                short zb = f2bf(z);
                inp0[(size_t)row * 224 + cc] = zb;
                inp1[(size_t)row * 288 + cc] = zb;
                inp2[(size_t)row * 288 + cc] = zb;
            }
        }
    }
}

// ---------------------------------------------------------------------------
// Gate MLP + softmax -> coef [2048,16].  Reads bf16 [z|c] from inp0.
// ---------------------------------------------------------------------------
__global__ __launch_bounds__(256) void gate_kernel(
    const short* __restrict__ inp0,
    const float* __restrict__ g0w, const float* __restrict__ g0b,
    const float* __restrict__ g1w, const float* __restrict__ g1b,
    const float* __restrict__ g2w, const float* __restrict__ g2b,
    float* __restrict__ coef)
{
    __shared__ float W0[NIN * NGH];
    __shared__ float W1[NGH * NGH];
    __shared__ float W2[NGH * NE];
    __shared__ float B0[NGH], B1[NGH], B2[NE];
    __shared__ float GIN[8][204];

    const int tid = threadIdx.x;
    for (int i = tid; i < NIN * NGH; i += 256) W0[i] = g0w[i];
    for (int i = tid; i < NGH * NGH; i += 256) W1[i] = g1w[i];
    for (int i = tid; i < NGH * NE;  i += 256) W2[i] = g2w[i];
    if (tid < NGH) { B0[tid] = g0b[tid]; B1[tid] = g1b[tid]; }
    if (tid < NE)  { B2[tid] = g2b[tid]; }

    const int row0 = blockIdx.x * 8;
    for (int idx = tid; idx < 8 * NIN; idx += 256) {
        int rr = idx / NIN, i = idx - rr * NIN;
        GIN[rr][i] = bf2f(inp0[(size_t)(row0 + rr) * 224 + i]);
    }
    __syncthreads();

    const int wave = tid >> 6, lane = tid & 63;
#pragma unroll
    for (int rw = 0; rw < 2; ++rw) {
        int rr = wave * 2 + rw;
        int row = row0 + rr;
        float a = B0[lane];
        for (int k = 0; k < NIN; ++k) a += GIN[rr][k] * W0[k * NGH + lane];
        float h = elu_f(a);
        float a1 = B1[lane];
#pragma unroll
        for (int k = 0; k < NGH; ++k) a1 += __shfl(h, k, 64) * W1[k * NGH + lane];
        float h2 = elu_f(a1);
        int o = lane & 15;
        float a2 = B2[o];
#pragma unroll
        for (int k = 0; k < NGH; ++k) a2 += __shfl(h2, k, 64) * W2[k * NE + o];
        float m = a2;
        for (int off = 1; off < 16; off <<= 1) m = fmaxf(m, __shfl_xor(m, off, 16));
        float ev = expf(a2 - m);
        float s = ev;
        for (int off = 1; off < 16; off <<= 1) s += __shfl_xor(s, off, 16);
        if (lane < 16) coef[row * 16 + lane] = ev / s;
    }
}

// ---------------------------------------------------------------------------
// moe_gemm: EPG experts per block; grid (OP/64, 32, 16/EPG).
// Depth-3 prefetch + counted vmcnt + raw barriers.
// ---------------------------------------------------------------------------
template<int KP, int OP, int EPG>
__global__ __launch_bounds__(256, 2) void moe_gemm(
    const short* __restrict__ inp,
    const short* __restrict__ Wt,
    const float* __restrict__ coef,
    float* __restrict__ partial)
{
    constexpr int NKS = KP / 32;
    constexpr int CHR = KP / 8;
    constexpr int NS = EPG * NKS;

    __shared__ short As[64 * KP];
    __shared__ short Bs[4][64 * 32];
    __shared__ float Cs[64][16];

    const int tid = threadIdx.x;
    const int lane = tid & 63;
    const int wid = tid >> 6;
    const int wm = wid >> 1, wn = wid & 1;
    const int bn = blockIdx.x, bm = blockIdx.y, kg = blockIdx.z;
    const int brow = bm * 64, bcol = bn * 64;
    const int wbase = wid * 1024;
    const int kseg = lane >> 4;

    // coef first (its compiler-inserted wait stays local)
    {
        int r = tid >> 2, q = tid & 3;
        float4 v = ((const float4*)(coef + (size_t)(brow + r) * 16))[q];
        *(float4*)&Cs[r][q * 4] = v;
    }
#pragma unroll
    for (int i = 0; i < (64 * KP / 8) / 256; ++i) {
        int ch = i * 256 + tid;
        int r = ch / CHR, kc = ch - r * CHR;
        int kcs = kc ^ ((r >> 1) & 3);
        gload16((char*)As + i * 4096 + wbase,
                inp + (size_t)(brow + r) * KP + kcs * 8);
    }
    auto stageB = [&](int buf, int s) {
        int ei = s / NKS, ks = s - ei * NKS;
        int e = kg * EPG + ei;
        int o = tid >> 2, sl = tid & 3;
        int sp = sl ^ ((o >> 1) & 3);
        gload16((char*)Bs[buf] + wbase,
                Wt + (size_t)(e * OP + bcol + o) * KP + ks * 32 + sp * 8);
    };
    stageB(0, 0); stageB(1, 1); stageB(2, 2);
    waitcnt_vm<2>();
    __builtin_amdgcn_s_barrier();

    const f32x4 zero4 = {0.0f, 0.0f, 0.0f, 0.0f};
    f32x4 outacc[2][2] = {{zero4, zero4}, {zero4, zero4}};
    f32x4 acc[2][2];

    for (int s = 0; s < NS; ++s) {
        int ei = s / NKS, ks = s - ei * NKS;
        if (ks == 0) {
            acc[0][0] = zero4; acc[0][1] = zero4;
            acc[1][0] = zero4; acc[1][1] = zero4;
        }
        if (s + 3 < NS) stageB((s + 3) & 3, s + 3);

        bf16x8 a[2], b[2];
#pragma unroll
        for (int mr = 0; mr < 2; ++mr) {
            int rr = wm * 32 + mr * 16 + (lane & 15);
            int kcr = ks * 4 + kseg;
            int kcp = kcr ^ ((rr >> 1) & 3);
            a[mr] = *(const bf16x8*)&As[rr * KP + kcp * 8];
        }
#pragma unroll
        for (int nr = 0; nr < 2; ++nr) {
            int oo = wn * 32 + nr * 16 + (lane & 15);
            int sp = kseg ^ ((oo >> 1) & 3);
            b[nr] = *(const bf16x8*)&Bs[s & 3][oo * 32 + sp * 8];
        }
#pragma unroll
        for (int mr = 0; mr < 2; ++mr)
#pragma unroll
            for (int nr = 0; nr < 2; ++nr)
                acc[mr][nr] = __builtin_amdgcn_mfma_f32_16x16x32_bf16(
                    a[mr], b[nr], acc[mr][nr], 0, 0, 0);

        if (ks == NKS - 1) {
            int e = kg * EPG + ei;
#pragma unroll
            for (int mr = 0; mr < 2; ++mr) {
                int rb = wm * 32 + mr * 16 + kseg * 4;
#pragma unroll
                for (int j = 0; j < 4; ++j) {
                    float cfv = Cs[rb + j][e];
#pragma unroll
                    for (int nr = 0; nr < 2; ++nr)
                        outacc[mr][nr][j] += cfv * acc[mr][nr][j];
                }
            }
        }
        loop_sync(s, NS);
    }

    float* pout = partial + (size_t)kg * 2048 * OP;
#pragma unroll
    for (int mr = 0; mr < 2; ++mr)
#pragma unroll
        for (int j = 0; j < 4; ++j) {
            int row = brow + wm * 32 + mr * 16 + kseg * 4 + j;
#pragma unroll
            for (int nr = 0; nr < 2; ++nr) {
                int col = bcol + wn * 32 + nr * 16 + (lane & 15);
                pout[(size_t)row * OP + col] = outacc[mr][nr][j];
            }
        }
}

// ---------------------------------------------------------------------------
// moe_finish: sum NKG partial slices + coef@bb; act; write bf16 panel / f32 out
// ---------------------------------------------------------------------------
template<int NP, int O, bool ACT, int NKG>
__global__ __launch_bounds__(256) void moe_finish(
    const float* __restrict__ partial,
    const float* __restrict__ coef,
    const float* __restrict__ bb,
    short* __restrict__ nxt,
    float* __restrict__ fout)
{
    __shared__ float bbs[16 * O];
    __shared__ float cfs[8][16];
    const int tid = threadIdx.x;
    const int row0 = blockIdx.x * 8;

    for (int i = tid; i < 16 * O; i += 256) bbs[i] = bb[i];
    if (tid < 128) cfs[tid >> 4][tid & 15] = coef[(row0 + (tid >> 4)) * 16 + (tid & 15)];
    __syncthreads();

    for (int idx = tid; idx < 8 * NP; idx += 256) {
        int r = idx / NP, o = idx - r * NP;
        if (o < O) {
            int row = row0 + r;
            float v = 0.0f;
#pragma unroll
            for (int kg = 0; kg < NKG; ++kg)
                v += partial[(size_t)(kg * 2048 + row) * NP + o];
            float bias = 0.0f;
#pragma unroll
            for (int e = 0; e < 16; ++e) bias += cfs[r][e] * bbs[e * O + o];
            v += bias;
            if (ACT) v = elu_f(v);
            if (nxt) nxt[(size_t)row * 288 + 32 + o] = f2bf(v);
            else     fout[(size_t)row * O + o] = v;
        }
    }
}

// ---------------------------------------------------------------------------
extern "C" void kernel_launch(void* const* d_in, const int* in_sizes, int n_in,
                              void* d_out, int out_size, void* d_ws, size_t ws_size,
                              hipStream_t stream)
{
    const float* x    = (const float*)d_in[0];
    const float* c    = (const float*)d_in[1];
    const float* eps  = (const float*)d_in[2];
    const float* fc1w = (const float*)d_in[3];
    const float* fc1b = (const float*)d_in[4];
    const float* fc2w = (const float*)d_in[5];
    const float* fc2b = (const float*)d_in[6];
    const float* muw  = (const float*)d_in[7];
    const float* mub  = (const float*)d_in[8];
    const float* lvw  = (const float*)d_in[9];
    const float* lvb  = (const float*)d_in[10];
    const float* g0w  = (const float*)d_in[11];
    const float* g0b  = (const float*)d_in[12];
    const float* g1w  = (const float*)d_in[13];
    const float* g1b  = (const float*)d_in[14];
    const float* g2w  = (const float*)d_in[15];
    const float* g2b  = (const float*)d_in[16];
    const float* w0   = (const float*)d_in[17];
    const float* b0   = (const float*)d_in[18];
    const float* w1   = (const float*)d_in[19];
    const float* b1   = (const float*)d_in[20];
    const float* w2   = (const float*)d_in[21];
    const float* b2   = (const float*)d_in[22];

    float* out       = (float*)d_out;
    float* out_layer = out;                       // [2048,171]
    float* out_mu    = out + NB * NOUT;           // [2048,32]
    float* out_lv    = out_mu + NB * NL;          // [2048,32]

    float* ws      = (float*)d_ws;
    float* partial = ws;                          // 8*2048*256 f32 = 16 MB
    float* cf      = partial + 8 * 2048 * 256;    // 2048*16 f32
    short* xc    = (short*)(cf + 32768);          // 2048*352
    short* xh1   = xc   + (size_t)2048 * 352;     // 2048*448
    short* xh2   = xh1  + (size_t)2048 * 448;     // 2048*448
    short* inp0  = xh2  + (size_t)2048 * 448;     // 2048*224
    short* inp1  = inp0 + (size_t)2048 * 224;     // 2048*288
    short* inp2  = inp1 + (size_t)2048 * 288;     // 2048*288
    short* fc1Wt = inp2 + (size_t)2048 * 288;     // 256*352
    short* fc2Wt = fc1Wt + 256 * 352;             // 256*448
    short* mlWt  = fc2Wt + 256 * 448;             // 64*448
    short* Wt0   = mlWt + 64 * 448;               // 16*256*224
    short* Wt1   = Wt0 + 16 * 256 * 224;          // 16*256*288
    short* Wt2   = Wt1 + 16 * 256 * 288;          // 16*192*288

    dim3 blk(256);

    // preprocessing: weight transposes + input panels in one launch
    prep_all<<<dim3(3140 + 2048), blk, 0, stream>>>(
        fc1w, fc2w, muw, lvw, w0, w1, w2,
        fc1Wt, fc2Wt, mlWt, mlWt + 32 * 448, Wt0, Wt1, Wt2,
        x, c, xc, xh1, xh2, inp0);

    // encoder chain (bf16 MFMA, pipelined)
    enc_gemm<352><<<dim3(4, 32), blk, 0, stream>>>(xc,  fc1Wt, fc1b, xh1, 448, 171);
    enc_gemm<448><<<dim3(4, 32), blk, 0, stream>>>(xh1, fc2Wt, fc2b, xh2, 448, 171);
    mulvz<<<dim3(1, 64), blk, 0, stream>>>(xh2, mlWt, mub, lvb, eps,
                                           out_mu, out_lv, inp0, inp1, inp2);
    gate_kernel<<<dim3(256), blk, 0, stream>>>(inp0, g0w, g0b, g1w, g1b, g2w, g2b, cf);

    // MoE layers: EPG=2 -> 8 expert-groups, 1024/768 blocks
    moe_gemm<224, 256, 2><<<dim3(4, 32, 8), blk, 0, stream>>>(inp0, Wt0, cf, partial);
    moe_finish<256, 256, true, 8><<<dim3(256), blk, 0, stream>>>(partial, cf, b0, inp1, nullptr);
    moe_gemm<288, 256, 2><<<dim3(4, 32, 8), blk, 0, stream>>>(inp1, Wt1, cf, partial);
    moe_finish<256, 256, true, 8><<<dim3(256), blk, 0, stream>>>(partial, cf, b1, inp2, nullptr);
    moe_gemm<288, 192, 2><<<dim3(3, 32, 8), blk, 0, stream>>>(inp2, Wt2, cf, partial);
    moe_finish<192, 171, false, 8><<<dim3(256), blk, 0, stream>>>(partial, cf, b2, nullptr, out_layer);
}

// Round 5
// 109.450 us; speedup vs baseline: 13.1730x; 1.1561x over previous
//
#include <hip/hip_runtime.h>
#include <math.h>

// Problem constants
#define NB   2048
#define NFC  171
#define NFR  171
#define NL   32
#define NH   256
#define NE   16
#define NGH  64
#define NIN  203   /* L + FC */
#define NINT 288   /* L + H  */
#define NOUT 171

typedef __attribute__((ext_vector_type(8))) short bf16x8;   // 8 bf16 in 4 VGPRs
typedef __attribute__((ext_vector_type(4))) float f32x4;    // MFMA acc

__device__ __forceinline__ float elu_f(float v) {
    return v > 0.0f ? v : expm1f(v);
}

// f32 -> bf16 bits, round-to-nearest-even
__device__ __forceinline__ short f2bf(float f) {
    unsigned u = __float_as_uint(f);
    unsigned r = (u + 0x7FFFu + ((u >> 16) & 1u)) >> 16;
    return (short)r;
}
__device__ __forceinline__ float bf2f(short s) {
    return __uint_as_float(((unsigned)(unsigned short)s) << 16);
}

// async global->LDS, 16 bytes per lane; lds base must be wave-uniform
__device__ __forceinline__ void gload16(void* lds, const void* g) {
    __builtin_amdgcn_global_load_lds(
        (const __attribute__((address_space(1))) unsigned*)g,
        (__attribute__((address_space(3))) unsigned*)lds, 16, 0, 0);
}

template<int N> __device__ __forceinline__ void waitcnt_vm() {
    if constexpr (N == 0)      asm volatile("s_waitcnt vmcnt(0) lgkmcnt(0)" ::: "memory");
    else if constexpr (N == 1) asm volatile("s_waitcnt vmcnt(1) lgkmcnt(0)" ::: "memory");
    else if constexpr (N == 2) asm volatile("s_waitcnt vmcnt(2) lgkmcnt(0)" ::: "memory");
    else                       asm volatile("s_waitcnt vmcnt(4) lgkmcnt(0)" ::: "memory");
}
// BK=32 path: 1 load per B-stage
__device__ __forceinline__ void loop_sync(int s, int NS) {
    if (s + 3 < NS)      waitcnt_vm<2>();
    else if (s + 2 < NS) waitcnt_vm<1>();
    else                 waitcnt_vm<0>();
    __builtin_amdgcn_s_barrier();
}
// BK=64 path: 2 loads per B-stage
__device__ __forceinline__ void loop_sync64(int s, int NS) {
    if (s + 3 < NS)      waitcnt_vm<4>();
    else if (s + 2 < NS) waitcnt_vm<2>();
    else                 waitcnt_vm<0>();
    __builtin_amdgcn_s_barrier();
}

// ---------------------------------------------------------------------------
// prep_all: blocks [0,3168) = weight transpose tiles; [3168, 3168+2048) = panels
// ---------------------------------------------------------------------------
__global__ __launch_bounds__(256) void prep_all(
    const float* s0, const float* s1, const float* s2, const float* s3,
    const float* s4, const float* s5, const float* s6,
    const float* s7, const float* s8, const float* s9,
    short* d0, short* d1, short* d2, short* d3,
    short* d4, short* d5, short* d6, short* d7, short* d8, short* d9,
    const float* __restrict__ x, const float* __restrict__ c,
    short* __restrict__ xc, short* __restrict__ xh1, short* __restrict__ xh2,
    short* __restrict__ inp0)
{
    __shared__ float T[32][33];
    const int tid = threadIdx.x;

    if (blockIdx.x >= 3168) {
        // ---- input panels, one block per batch row ----
        const int b = blockIdx.x - 3168;
        for (int i = tid; i < 384; i += 256) {
            float v = (i < 171) ? x[b * 171 + i] : ((i < 342) ? c[b * 171 + (i - 171)] : 0.0f);
            xc[(size_t)b * 384 + i] = f2bf(v);
        }
        for (int i = tid; i < 171; i += 256) {
            short v = f2bf(x[b * 171 + i]);
            xh1[(size_t)b * 448 + i] = v;
            xh2[(size_t)b * 448 + i] = v;
        }
        for (int i = tid; i < 21; i += 256) {
            xh1[(size_t)b * 448 + 427 + i] = 0;
            xh2[(size_t)b * 448 + 427 + i] = 0;
        }
        for (int i = tid; i < 192; i += 256) {
            inp0[(size_t)b * 224 + 32 + i] = (i < 171) ? f2bf(c[b * 171 + i]) : (short)0;
        }
        return;
    }

    // ---- weight transpose tiles (10 segments) ----
    constexpr int K_[10]   = {342, 427, 427, 427, 203, 288, 288, 203,  64,  64};
    constexpr int O_[10]   = {256, 256,  32,  32, 256, 256, 171,  64,  64,  16};
    constexpr int KP_[10]  = {384, 448, 448, 448, 224, 288, 288, 224,  64,  64};
    constexpr int OP_[10]  = {256, 256,  64,  64, 256, 256, 192,  64,  64,  32};
    constexpr int nKT_[10] = { 12,  14,  14,  14,   7,   9,   9,   7,   2,   2};
    constexpr int tpe_[10] = { 96, 112,  14,  14,  56,  72,  54,  14,   4,   2};
    constexpr int st_[10]  = {  0,  96, 208, 222, 236,1132,2284,3148,3162,3166};
    const float* srcs[10] = {s0, s1, s2, s3, s4, s5, s6, s7, s8, s9};
    short*       dsts[10] = {d0, d1, d2, d3, d4, d5, d6, d7, d8, d9};

    int t = blockIdx.x;
    int s = 0;
    while (s < 9 && t >= st_[s + 1]) ++s;
    int local = t - st_[s];
    int e = local / tpe_[s];
    int rem = local - e * tpe_[s];
    int ox = rem / nKT_[s];
    int ky = rem - ox * nKT_[s];
    const int K = K_[s], O = O_[s], KP = KP_[s], OP = OP_[s];
    const float* src = srcs[s];
    short* dst = dsts[s];

    const int cc = tid & 31, r0 = tid >> 5;
#pragma unroll
    for (int i = 0; i < 4; ++i) {
        int r = r0 + i * 8;
        int gk = ky * 32 + r, go = ox * 32 + cc;
        T[r][cc] = (gk < K && go < O) ? src[((size_t)e * K + gk) * O + go] : 0.0f;
    }
    __syncthreads();
#pragma unroll
    for (int i = 0; i < 4; ++i) {
        int r = r0 + i * 8;
        int go = ox * 32 + r, gk = ky * 32 + cc;
        dst[((size_t)e * OP + go) * KP + gk] = f2bf(T[cc][r]);
    }
}

// ---------------------------------------------------------------------------
// enc_gemm: BM=32, BN=64, BK=64.  grid (NO/64, 64)
// dst[row][dstoff+col] = bf16(ELU(A[row,:] @ Wt[col,:] + bias[col]))
// ---------------------------------------------------------------------------
template<int KP>
__global__ __launch_bounds__(256, 2) void enc_gemm(
    const short* __restrict__ A,
    const short* __restrict__ Wt,
    const float* __restrict__ bias,
    short* __restrict__ dst, int dstld, int dstoff)
{
    constexpr int NKS = KP / 64;
    constexpr int CHR = KP / 8;

    __shared__ short As[32 * KP];
    __shared__ short Bs[4][64 * 64];

    const int tid = threadIdx.x;
    const int lane = tid & 63;
    const int wid = tid >> 6;
    const int wm = wid & 1, wn = wid >> 1;
    const int brow = blockIdx.y * 32, bcol = blockIdx.x * 64;
    const int wbase = wid * 1024;
    const int kseg = lane >> 4;

#pragma unroll
    for (int i = 0; i < (32 * CHR) / 256; ++i) {
        int ch = i * 256 + tid;
        int r = ch / CHR, kc = ch - r * CHR;
        int kcs = kc ^ ((r >> 1) & 3);
        gload16((char*)As + i * 4096 + wbase, A + (size_t)(brow + r) * KP + kcs * 8);
    }
    auto stageB = [&](int buf, int ks) {
#pragma unroll
        for (int g = 0; g < 2; ++g) {
            int ch = g * 256 + tid;
            int o = ch >> 3, sl = ch & 7;
            int sp = sl ^ ((o >> 1) & 3);
            gload16((char*)Bs[buf] + g * 4096 + wbase,
                    Wt + (size_t)(bcol + o) * KP + ks * 64 + sp * 8);
        }
    };
    stageB(0, 0); stageB(1, 1); stageB(2, 2);
    waitcnt_vm<4>();
    __builtin_amdgcn_s_barrier();

    const f32x4 zero4 = {0.0f, 0.0f, 0.0f, 0.0f};
    f32x4 acc[2] = {zero4, zero4};

    for (int s = 0; s < NKS; ++s) {
        if (s + 3 < NKS) stageB((s + 3) & 3, s + 3);
#pragma unroll
        for (int kk = 0; kk < 2; ++kk) {
            bf16x8 a, b[2];
            int rr = wm * 16 + (lane & 15);
            int kcp = (s * 8 + kk * 4 + kseg) ^ ((rr >> 1) & 3);
            a = *(const bf16x8*)&As[rr * KP + kcp * 8];
#pragma unroll
            for (int nr = 0; nr < 2; ++nr) {
                int oo = wn * 32 + nr * 16 + (lane & 15);
                int sp = (kk * 4 + kseg) ^ ((oo >> 1) & 3);
                b[nr] = *(const bf16x8*)&Bs[s & 3][oo * 64 + sp * 8];
            }
#pragma unroll
            for (int nr = 0; nr < 2; ++nr)
                acc[nr] = __builtin_amdgcn_mfma_f32_16x16x32_bf16(a, b[nr], acc[nr], 0, 0, 0);
        }
        loop_sync64(s, NKS);
    }

#pragma unroll
    for (int j = 0; j < 4; ++j) {
        int row = brow + wm * 16 + kseg * 4 + j;
#pragma unroll
        for (int nr = 0; nr < 2; ++nr) {
            int col = bcol + wn * 32 + nr * 16 + (lane & 15);
            float v = acc[nr][j] + bias[col];
            dst[(size_t)row * dstld + dstoff + col] = f2bf(elu_f(v));
        }
    }
}

// ---------------------------------------------------------------------------
// mulvz_gate: BM=32, grid (1,64).
//  [mu|lv] = xh2 @ mlWt^T + bias -> d_out f32;  z -> bf16 panels (global+LDS);
//  then in-LDS gate MLP (g0/g1/g2 bf16 MFMA) + softmax -> coef.
// Waves: wm=wid&1 (16-row half), wn=wid>>1 (32-col half: 0=mu, 1=lv).
// ---------------------------------------------------------------------------
__global__ __launch_bounds__(256) void mulvz_gate(
    const short* __restrict__ A,             // xh2 [2048][448]
    const short* __restrict__ Wt,            // mlWt [64][448]
    const float* __restrict__ mub, const float* __restrict__ lvb,
    const float* __restrict__ eps,
    const short* __restrict__ g0wt,          // [64][224]
    const short* __restrict__ g1wt,          // [64][64]
    const short* __restrict__ g2wt,          // [32][64] rows 16..31 zero
    const float* __restrict__ g0b, const float* __restrict__ g1b,
    const float* __restrict__ g2b,
    float* __restrict__ mu_out, float* __restrict__ lv_out,
    short* __restrict__ inp0, short* __restrict__ inp1, short* __restrict__ inp2,
    float* __restrict__ coef)
{
    constexpr int KP = 448;
    constexpr int NKS = KP / 64;   // 7
    constexpr int CHR = KP / 8;    // 56

    __shared__ short As[32 * 448];
    __shared__ short Bs[4][64 * 64];
    __shared__ float Els[32][32];
    __shared__ short gA[32 * 224];
    __shared__ short g0s[64 * 224];
    __shared__ short g1s[64 * 64];
    __shared__ short g2s[32 * 64];
    __shared__ short hA[32 * 64];
    __shared__ short hB[32 * 64];

    const int tid = threadIdx.x;
    const int lane = tid & 63;
    const int wid = tid >> 6;
    const int wm = wid & 1, wn = wid >> 1;
    const int brow = blockIdx.y * 32;
    const int wbase = wid * 1024;
    const int kseg = lane >> 4;
    const int l15 = lane & 15;

    // ---- A panel (7 gloads) ----
#pragma unroll
    for (int i = 0; i < 7; ++i) {
        int ch = i * 256 + tid;
        int r = ch / CHR, kc = ch - r * CHR;
        int kcs = kc ^ ((r >> 1) & 3);
        gload16((char*)As + i * 4096 + wbase, A + (size_t)(brow + r) * KP + kcs * 8);
    }
    // ---- gate A panel c-part from inp0 (chunks 0..3 stale, overwritten later) ----
#pragma unroll
    for (int i = 0; i < 4; ++i) {
        int ch = i * 256 + tid;
        if (ch < 896) {
            int r = ch / 28, kc = ch - r * 28;
            int kcs = kc ^ ((r >> 1) & 3);
            gload16((char*)gA + i * 4096 + wbase, inp0 + (size_t)(brow + r) * 224 + kcs * 8);
        }
    }
    // ---- gate weights ----
#pragma unroll
    for (int i = 0; i < 7; ++i) {
        int ch = i * 256 + tid;
        int r = ch / 28, kc = ch - r * 28;
        int kcs = kc ^ ((r >> 1) & 3);
        gload16((char*)g0s + i * 4096 + wbase, g0wt + (size_t)r * 224 + kcs * 8);
    }
#pragma unroll
    for (int i = 0; i < 2; ++i) {
        int ch = i * 256 + tid;
        int r = ch >> 3, kc = ch & 7;
        int kcs = kc ^ ((r >> 1) & 3);
        gload16((char*)g1s + i * 4096 + wbase, g1wt + (size_t)r * 64 + kcs * 8);
    }
    {
        int ch = tid;
        int r = ch >> 3, kc = ch & 7;
        int kcs = kc ^ ((r >> 1) & 3);
        gload16((char*)g2s + wbase, g2wt + (size_t)r * 64 + kcs * 8);
    }
    // ---- B double-buffer ----
    auto stageB = [&](int buf, int ks) {
#pragma unroll
        for (int g = 0; g < 2; ++g) {
            int ch = g * 256 + tid;
            int o = ch >> 3, sl = ch & 7;
            int sp = sl ^ ((o >> 1) & 3);
            gload16((char*)Bs[buf] + g * 4096 + wbase,
                    Wt + (size_t)o * KP + ks * 64 + sp * 8);
        }
    };
    stageB(0, 0); stageB(1, 1); stageB(2, 2);
    waitcnt_vm<4>();
    __builtin_amdgcn_s_barrier();

    const f32x4 zero4 = {0.0f, 0.0f, 0.0f, 0.0f};
    f32x4 acc[2] = {zero4, zero4};

    for (int s = 0; s < NKS; ++s) {
        if (s + 3 < NKS) stageB((s + 3) & 3, s + 3);
#pragma unroll
        for (int kk = 0; kk < 2; ++kk) {
            bf16x8 a, b[2];
            int rr = wm * 16 + l15;
            int kcp = (s * 8 + kk * 4 + kseg) ^ ((rr >> 1) & 3);
            a = *(const bf16x8*)&As[rr * KP + kcp * 8];
#pragma unroll
            for (int nr = 0; nr < 2; ++nr) {
                int oo = wn * 32 + nr * 16 + l15;
                int sp = (kk * 4 + kseg) ^ ((oo >> 1) & 3);
                b[nr] = *(const bf16x8*)&Bs[s & 3][oo * 64 + sp * 8];
            }
#pragma unroll
            for (int nr = 0; nr < 2; ++nr)
                acc[nr] = __builtin_amdgcn_mfma_f32_16x16x32_bf16(a, b[nr], acc[nr], 0, 0, 0);
        }
        loop_sync64(s, NKS);
    }

    // ---- mu / lv epilogue ----
#pragma unroll
    for (int j = 0; j < 4; ++j) {
        int rl = wm * 16 + kseg * 4 + j;
        int row = brow + rl;
#pragma unroll
        for (int nr = 0; nr < 2; ++nr) {
            int cc = nr * 16 + l15;              // 0..31
            if (wn == 1) {
                float v = acc[nr][j] + lvb[cc];
                lv_out[(size_t)row * 32 + cc] = v;
                Els[rl][cc] = expf(0.5f * v);
            } else {
                float v = acc[nr][j] + mub[cc];
                mu_out[(size_t)row * 32 + cc] = v;
                acc[nr][j] = v;
            }
        }
    }
    __syncthreads();
    // ---- z: global panels + gate A panel z-part ----
    if (wn == 0) {
#pragma unroll
        for (int j = 0; j < 4; ++j) {
            int rl = wm * 16 + kseg * 4 + j;
            int row = brow + rl;
#pragma unroll
            for (int nr = 0; nr < 2; ++nr) {
                int cc = nr * 16 + l15;
                float z = acc[nr][j] + eps[(size_t)row * 32 + cc] * Els[rl][cc];
                short zb = f2bf(z);
                inp0[(size_t)row * 224 + cc] = zb;
                inp1[(size_t)row * 288 + cc] = zb;
                inp2[(size_t)row * 288 + cc] = zb;
                int swz = (cc >> 3) ^ ((rl >> 1) & 3);
                gA[rl * 224 + swz * 8 + (cc & 7)] = zb;
            }
        }
    }
    __syncthreads();

    // ---- gate g0: [32,224] @ [224,64] ----
    {
        f32x4 g[2] = {zero4, zero4};
#pragma unroll
        for (int s = 0; s < 7; ++s) {
            bf16x8 a, b[2];
            int rr = wm * 16 + l15;
            int kcp = (s * 4 + kseg) ^ ((rr >> 1) & 3);
            a = *(const bf16x8*)&gA[rr * 224 + kcp * 8];
#pragma unroll
            for (int nr = 0; nr < 2; ++nr) {
                int oo = wn * 32 + nr * 16 + l15;
                int sp = (s * 4 + kseg) ^ ((oo >> 1) & 3);
                b[nr] = *(const bf16x8*)&g0s[oo * 224 + sp * 8];
            }
#pragma unroll
            for (int nr = 0; nr < 2; ++nr)
                g[nr] = __builtin_amdgcn_mfma_f32_16x16x32_bf16(a, b[nr], g[nr], 0, 0, 0);
        }
#pragma unroll
        for (int j = 0; j < 4; ++j) {
            int rl = wm * 16 + kseg * 4 + j;
#pragma unroll
            for (int nr = 0; nr < 2; ++nr) {
                int cc = wn * 32 + nr * 16 + l15;
                float v = elu_f(g[nr][j] + g0b[cc]);
                int swz = (cc >> 3) ^ ((rl >> 1) & 3);
                hA[rl * 64 + swz * 8 + (cc & 7)] = f2bf(v);
            }
        }
    }
    __syncthreads();
    // ---- gate g1: [32,64] @ [64,64] ----
    {
        f32x4 g[2] = {zero4, zero4};
#pragma unroll
        for (int s = 0; s < 2; ++s) {
            bf16x8 a, b[2];
            int rr = wm * 16 + l15;
            int kcp = (s * 4 + kseg) ^ ((rr >> 1) & 3);
            a = *(const bf16x8*)&hA[rr * 64 + kcp * 8];
#pragma unroll
            for (int nr = 0; nr < 2; ++nr) {
                int oo = wn * 32 + nr * 16 + l15;
                int sp = (s * 4 + kseg) ^ ((oo >> 1) & 3);
                b[nr] = *(const bf16x8*)&g1s[oo * 64 + sp * 8];
            }
#pragma unroll
            for (int nr = 0; nr < 2; ++nr)
                g[nr] = __builtin_amdgcn_mfma_f32_16x16x32_bf16(a, b[nr], g[nr], 0, 0, 0);
        }
#pragma unroll
        for (int j = 0; j < 4; ++j) {
            int rl = wm * 16 + kseg * 4 + j;
#pragma unroll
            for (int nr = 0; nr < 2; ++nr) {
                int cc = wn * 32 + nr * 16 + l15;
                float v = elu_f(g[nr][j] + g1b[cc]);
                int swz = (cc >> 3) ^ ((rl >> 1) & 3);
                hB[rl * 64 + swz * 8 + (cc & 7)] = f2bf(v);
            }
        }
    }
    __syncthreads();
    // ---- gate g2 + softmax (waves wn==0 only) ----
    if (wn == 0) {
        f32x4 g = zero4;
#pragma unroll
        for (int s = 0; s < 2; ++s) {
            bf16x8 a, b;
            int rr = wm * 16 + l15;
            int kcp = (s * 4 + kseg) ^ ((rr >> 1) & 3);
            a = *(const bf16x8*)&hB[rr * 64 + kcp * 8];
            int oo = l15;
            int sp = (s * 4 + kseg) ^ ((oo >> 1) & 3);
            b = *(const bf16x8*)&g2s[oo * 64 + sp * 8];
            g = __builtin_amdgcn_mfma_f32_16x16x32_bf16(a, b, g, 0, 0, 0);
        }
        float bv = g2b[l15];
#pragma unroll
        for (int j = 0; j < 4; ++j) {
            int rl = wm * 16 + kseg * 4 + j;
            int row = brow + rl;
            float a2 = g[j] + bv;
            float m = a2;
            for (int off = 1; off < 16; off <<= 1) m = fmaxf(m, __shfl_xor(m, off, 16));
            float ev = expf(a2 - m);
            float sm = ev;
            for (int off = 1; off < 16; off <<= 1) sm += __shfl_xor(sm, off, 16);
            coef[(size_t)row * 16 + l15] = ev / sm;
        }
    }
}

// ---------------------------------------------------------------------------
// moe_gemm: EPG experts per block; grid (OP/64, 32, 16/EPG).  BK=32 (verified).
// ---------------------------------------------------------------------------
template<int KP, int OP, int EPG>
__global__ __launch_bounds__(256, 2) void moe_gemm(
    const short* __restrict__ inp,
    const short* __restrict__ Wt,
    const float* __restrict__ coef,
    float* __restrict__ partial)
{
    constexpr int NKS = KP / 32;
    constexpr int CHR = KP / 8;
    constexpr int NS = EPG * NKS;

    __shared__ short As[64 * KP];
    __shared__ short Bs[4][64 * 32];
    __shared__ float Cs[64][16];

    const int tid = threadIdx.x;
    const int lane = tid & 63;
    const int wid = tid >> 6;
    const int wm = wid >> 1, wn = wid & 1;
    const int bn = blockIdx.x, bm = blockIdx.y, kg = blockIdx.z;
    const int brow = bm * 64, bcol = bn * 64;
    const int wbase = wid * 1024;
    const int kseg = lane >> 4;

    {
        int r = tid >> 2, q = tid & 3;
        float4 v = ((const float4*)(coef + (size_t)(brow + r) * 16))[q];
        *(float4*)&Cs[r][q * 4] = v;
    }
#pragma unroll
    for (int i = 0; i < (64 * KP / 8) / 256; ++i) {
        int ch = i * 256 + tid;
        int r = ch / CHR, kc = ch - r * CHR;
        int kcs = kc ^ ((r >> 1) & 3);
        gload16((char*)As + i * 4096 + wbase,
                inp + (size_t)(brow + r) * KP + kcs * 8);
    }
    auto stageB = [&](int buf, int s) {
        int ei = s / NKS, ks = s - ei * NKS;
        int e = kg * EPG + ei;
        int o = tid >> 2, sl = tid & 3;
        int sp = sl ^ ((o >> 1) & 3);
        gload16((char*)Bs[buf] + wbase,
                Wt + (size_t)(e * OP + bcol + o) * KP + ks * 32 + sp * 8);
    };
    stageB(0, 0); stageB(1, 1); stageB(2, 2);
    waitcnt_vm<2>();
    __builtin_amdgcn_s_barrier();

    const f32x4 zero4 = {0.0f, 0.0f, 0.0f, 0.0f};
    f32x4 outacc[2][2] = {{zero4, zero4}, {zero4, zero4}};
    f32x4 acc[2][2];

    for (int s = 0; s < NS; ++s) {
        int ei = s / NKS, ks = s - ei * NKS;
        if (ks == 0) {
            acc[0][0] = zero4; acc[0][1] = zero4;
            acc[1][0] = zero4; acc[1][1] = zero4;
        }
        if (s + 3 < NS) stageB((s + 3) & 3, s + 3);

        bf16x8 a[2], b[2];
#pragma unroll
        for (int mr = 0; mr < 2; ++mr) {
            int rr = wm * 32 + mr * 16 + (lane & 15);
            int kcr = ks * 4 + kseg;
            int kcp = kcr ^ ((rr >> 1) & 3);
            a[mr] = *(const bf16x8*)&As[rr * KP + kcp * 8];
        }
#pragma unroll
        for (int nr = 0; nr < 2; ++nr) {
            int oo = wn * 32 + nr * 16 + (lane & 15);
            int sp = kseg ^ ((oo >> 1) & 3);
            b[nr] = *(const bf16x8*)&Bs[s & 3][oo * 32 + sp * 8];
        }
#pragma unroll
        for (int mr = 0; mr < 2; ++mr)
#pragma unroll
            for (int nr = 0; nr < 2; ++nr)
                acc[mr][nr] = __builtin_amdgcn_mfma_f32_16x16x32_bf16(
                    a[mr], b[nr], acc[mr][nr], 0, 0, 0);

        if (ks == NKS - 1) {
            int e = kg * EPG + ei;
#pragma unroll
            for (int mr = 0; mr < 2; ++mr) {
                int rb = wm * 32 + mr * 16 + kseg * 4;
#pragma unroll
                for (int j = 0; j < 4; ++j) {
                    float cfv = Cs[rb + j][e];
#pragma unroll
                    for (int nr = 0; nr < 2; ++nr)
                        outacc[mr][nr][j] += cfv * acc[mr][nr][j];
                }
            }
        }
        loop_sync(s, NS);
    }

    float* pout = partial + (size_t)kg * 2048 * OP;
#pragma unroll
    for (int mr = 0; mr < 2; ++mr)
#pragma unroll
        for (int j = 0; j < 4; ++j) {
            int row = brow + wm * 32 + mr * 16 + kseg * 4 + j;
#pragma unroll
            for (int nr = 0; nr < 2; ++nr) {
                int col = bcol + wn * 32 + nr * 16 + (lane & 15);
                pout[(size_t)row * OP + col] = outacc[mr][nr][j];
            }
        }
}

// ---------------------------------------------------------------------------
// moe_finish: sum NKG partial slices (float4) + coef@bb; act; write.
// ---------------------------------------------------------------------------
template<int NP, int O, bool ACT, int NKG>
__global__ __launch_bounds__(256) void moe_finish(
    const float* __restrict__ partial,
    const float* __restrict__ coef,
    const float* __restrict__ bb,
    short* __restrict__ nxt,
    float* __restrict__ fout)
{
    __shared__ float bbs[16 * O];
    __shared__ float cfs[8][16];
    const int tid = threadIdx.x;
    const int row0 = blockIdx.x * 8;

    for (int i = tid; i < 16 * O; i += 256) bbs[i] = bb[i];
    if (tid < 128) cfs[tid >> 4][tid & 15] = coef[(row0 + (tid >> 4)) * 16 + (tid & 15)];
    __syncthreads();

    constexpr int NG = NP / 4;
    for (int idx = tid; idx < 8 * NG; idx += 256) {
        int r = idx / NG, og = idx - r * NG;
        int o = og * 4;
        int row = row0 + r;
        float4 v = {0.f, 0.f, 0.f, 0.f};
#pragma unroll
        for (int kg = 0; kg < NKG; ++kg) {
            float4 p = *(const float4*)&partial[(size_t)(kg * 2048 + row) * NP + o];
            v.x += p.x; v.y += p.y; v.z += p.z; v.w += p.w;
        }
        float vv[4] = {v.x, v.y, v.z, v.w};
#pragma unroll
        for (int t = 0; t < 4; ++t) {
            int oo = o + t;
            if (oo < O) {
                float bias = 0.0f;
#pragma unroll
                for (int e = 0; e < 16; ++e) bias += cfs[r][e] * bbs[e * O + oo];
                float val = vv[t] + bias;
                if (ACT) val = elu_f(val);
                if (nxt) nxt[(size_t)row * 288 + 32 + oo] = f2bf(val);
                else     fout[(size_t)row * O + oo] = val;
            }
        }
    }
}

// ---------------------------------------------------------------------------
extern "C" void kernel_launch(void* const* d_in, const int* in_sizes, int n_in,
                              void* d_out, int out_size, void* d_ws, size_t ws_size,
                              hipStream_t stream)
{
    const float* x    = (const float*)d_in[0];
    const float* c    = (const float*)d_in[1];
    const float* eps  = (const float*)d_in[2];
    const float* fc1w = (const float*)d_in[3];
    const float* fc1b = (const float*)d_in[4];
    const float* fc2w = (const float*)d_in[5];
    const float* fc2b = (const float*)d_in[6];
    const float* muw  = (const float*)d_in[7];
    const float* mub  = (const float*)d_in[8];
    const float* lvw  = (const float*)d_in[9];
    const float* lvb  = (const float*)d_in[10];
    const float* g0w  = (const float*)d_in[11];
    const float* g0b  = (const float*)d_in[12];
    const float* g1w  = (const float*)d_in[13];
    const float* g1b  = (const float*)d_in[14];
    const float* g2w  = (const float*)d_in[15];
    const float* g2b  = (const float*)d_in[16];
    const float* w0   = (const float*)d_in[17];
    const float* b0   = (const float*)d_in[18];
    const float* w1   = (const float*)d_in[19];
    const float* b1   = (const float*)d_in[20];
    const float* w2   = (const float*)d_in[21];
    const float* b2   = (const float*)d_in[22];

    float* out       = (float*)d_out;
    float* out_layer = out;                       // [2048,171]
    float* out_mu    = out + NB * NOUT;           // [2048,32]
    float* out_lv    = out_mu + NB * NL;          // [2048,32]

    float* ws      = (float*)d_ws;
    float* partial = ws;                          // 8*2048*256 f32 = 16 MB
    float* cf      = partial + 8 * 2048 * 256;    // 2048*16 f32
    short* xc    = (short*)(cf + 32768);          // 2048*384
    short* xh1   = xc   + (size_t)2048 * 384;     // 2048*448
    short* xh2   = xh1  + (size_t)2048 * 448;     // 2048*448
    short* inp0  = xh2  + (size_t)2048 * 448;     // 2048*224
    short* inp1  = inp0 + (size_t)2048 * 224;     // 2048*288
    short* inp2  = inp1 + (size_t)2048 * 288;     // 2048*288
    short* fc1Wt = inp2 + (size_t)2048 * 288;     // 256*384
    short* fc2Wt = fc1Wt + 256 * 384;             // 256*448
    short* mlWt  = fc2Wt + 256 * 448;             // 64*448
    short* Wt0   = mlWt + 64 * 448;               // 16*256*224
    short* Wt1   = Wt0 + 16 * 256 * 224;          // 16*256*288
    short* Wt2   = Wt1 + 16 * 256 * 288;          // 16*192*288
    short* g0wt  = Wt2 + 16 * 192 * 288;          // 64*224
    short* g1wt  = g0wt + 64 * 224;               // 64*64
    short* g2wt  = g1wt + 64 * 64;                // 32*64

    dim3 blk(256);

    // preprocessing: all weight transposes + input panels in one launch
    prep_all<<<dim3(3168 + 2048), blk, 0, stream>>>(
        fc1w, fc2w, muw, lvw, w0, w1, w2, g0w, g1w, g2w,
        fc1Wt, fc2Wt, mlWt, mlWt + 32 * 448, Wt0, Wt1, Wt2, g0wt, g1wt, g2wt,
        x, c, xc, xh1, xh2, inp0);

    // encoder chain (bf16 MFMA, BM=32/BK=64 pipelined)
    enc_gemm<384><<<dim3(4, 64), blk, 0, stream>>>(xc,  fc1Wt, fc1b, xh1, 448, 171);
    enc_gemm<448><<<dim3(4, 64), blk, 0, stream>>>(xh1, fc2Wt, fc2b, xh2, 448, 171);
    // mu/lv/z + fused gate
    mulvz_gate<<<dim3(1, 64), blk, 0, stream>>>(
        xh2, mlWt, mub, lvb, eps, g0wt, g1wt, g2wt, g0b, g1b, g2b,
        out_mu, out_lv, inp0, inp1, inp2, cf);

    // MoE layers: EPG=2 -> 8 expert-groups
    moe_gemm<224, 256, 2><<<dim3(4, 32, 8), blk, 0, stream>>>(inp0, Wt0, cf, partial);
    moe_finish<256, 256, true, 8><<<dim3(256), blk, 0, stream>>>(partial, cf, b0, inp1, nullptr);
    moe_gemm<288, 256, 2><<<dim3(4, 32, 8), blk, 0, stream>>>(inp1, Wt1, cf, partial);
    moe_finish<256, 256, true, 8><<<dim3(256), blk, 0, stream>>>(partial, cf, b1, inp2, nullptr);
    moe_gemm<288, 192, 2><<<dim3(3, 32, 8), blk, 0, stream>>>(inp2, Wt2, cf, partial);
    moe_finish<192, 171, false, 8><<<dim3(256), blk, 0, stream>>>(partial, cf, b2, nullptr, out_layer);
}